// Round 1
// baseline (2347.119 us; speedup 1.0000x reference)
//
#include <hip/hip_runtime.h>
#include <math.h>

typedef long long i64;

#define TEMP_ISQ 0.047245559f   // 1/sqrt(448)

// ---------------- GEMM: out[M,N](+bias) = Aop(A)[M,Kd] @ W[Kd,N] ----------------
// AMODE: 0 plain, 1 phr-pool (row r = 0.5*(row 2r + row 2r+1)), 2 row-scaled (rowScale[r]*A[r])
// OT:    0 normal store, 1 transposed store out[c*ldO + r]
template<int AMODE, int OT>
__global__ __launch_bounds__(256)
void gemm_f32(const float* __restrict__ Ab, i64 sA,
              const float* __restrict__ Wb, i64 sW,
              const float* __restrict__ bias,
              float* __restrict__ Ob, i64 sO,
              int M, int Kd, int Nn, int ldA, int ldW, int ldO,
              const float* __restrict__ rowScale)
{
  const int z = blockIdx.z;
  const float* A = Ab + (i64)z * sA;
  const float* W = Wb + (i64)z * sW;
  float* out = Ob + (i64)z * sO;
  const float* rs = (AMODE == 2) ? (rowScale + (i64)z * M) : nullptr;

  __shared__ float As[16][68];   // [k][m], stride 68 -> <=2-way bank conflict (free)
  __shared__ float Ws[16][68];   // [k][n]

  const int tid = threadIdx.x;
  const int m0 = blockIdx.y * 64, n0 = blockIdx.x * 64;
  const int tx = tid & 15, ty = tid >> 4;
  const int la_k = tid & 15, la_m0 = tid >> 4;
  const int lw_n = tid & 63, lw_k0 = tid >> 6;

  float acc[4][4];
  #pragma unroll
  for (int i = 0; i < 4; ++i)
    #pragma unroll
    for (int j = 0; j < 4; ++j) acc[i][j] = 0.f;

  for (int k0 = 0; k0 < Kd; k0 += 16) {
    #pragma unroll
    for (int p = 0; p < 4; ++p) {
      int m  = la_m0 + p * 16;
      int gm = m0 + m;
      int gk = k0 + la_k;
      float v = 0.f;
      if (gm < M) {
        if (AMODE == 0)      v = A[(i64)gm * ldA + gk];
        else if (AMODE == 1) v = 0.5f * (A[(i64)(2*gm) * ldA + gk] + A[(i64)(2*gm+1) * ldA + gk]);
        else                 v = rs[gm] * A[(i64)gm * ldA + gk];
      }
      As[la_k][m] = v;
    }
    #pragma unroll
    for (int p = 0; p < 4; ++p) {
      int k  = lw_k0 + p * 4;
      int gk = k0 + k, gn = n0 + lw_n;
      float v = 0.f;
      if (gn < Nn) v = W[(i64)gk * ldW + gn];
      Ws[k][lw_n] = v;
    }
    __syncthreads();
    #pragma unroll
    for (int kk = 0; kk < 16; ++kk) {
      float4 a4 = *reinterpret_cast<const float4*>(&As[kk][ty * 4]);
      float4 b4 = *reinterpret_cast<const float4*>(&Ws[kk][tx * 4]);
      float av[4] = {a4.x, a4.y, a4.z, a4.w};
      float bv[4] = {b4.x, b4.y, b4.z, b4.w};
      #pragma unroll
      for (int i = 0; i < 4; ++i)
        #pragma unroll
        for (int j = 0; j < 4; ++j)
          acc[i][j] = fmaf(av[i], bv[j], acc[i][j]);
    }
    __syncthreads();
  }

  #pragma unroll
  for (int i = 0; i < 4; ++i) {
    int r = m0 + ty * 4 + i;
    if (r >= M) continue;
    #pragma unroll
    for (int j = 0; j < 4; ++j) {
      int c = n0 + tx * 4 + j;
      if (c >= Nn) continue;
      float v = acc[i][j] + (bias ? bias[c] : 0.f);
      if (OT == 0) out[(i64)r * ldO + c] = v;
      else         out[(i64)c * ldO + r] = v;
    }
  }
}

// ---------------- small kernels ----------------

// copy video_feat into combine rows 256..511 (float4)
__global__ void vcopy_kernel(const float* __restrict__ video, float* __restrict__ combine) {
  i64 i = (i64)blockIdx.x * blockDim.x + threadIdx.x;   // float4 index into [B,256,1024]
  const i64 total = (i64)32 * 256 * 1024 / 4;
  if (i >= total) return;
  i64 b = i / 65536;          // 256*1024/4
  i64 r = i - b * 65536;
  const float4* src = (const float4*)video;
  float4* dst = (float4*)combine;
  dst[b * 131072 + 65536 + r] = src[i];  // 512*1024/4 = 131072
}

// softmax over attn_a rows (128 cols), write TRANSPOSED: attnAT[b,k,m]
__global__ void softmax_attn_a(const float* __restrict__ logits, float* __restrict__ outT) {
  int gw = (int)((blockIdx.x * (i64)blockDim.x + threadIdx.x) >> 6);
  int lane = threadIdx.x & 63;
  if (gw >= 32 * 512) return;
  int b = gw >> 9, m = gw & 511;
  const float* p = logits + (i64)gw * 128;
  float x0 = p[lane], x1 = p[lane + 64];
  float mx = fmaxf(x0, x1);
  #pragma unroll
  for (int o = 32; o; o >>= 1) mx = fmaxf(mx, __shfl_xor(mx, o));
  float e0 = expf(x0 - mx), e1 = expf(x1 - mx);
  float s = e0 + e1;
  #pragma unroll
  for (int o = 32; o; o >>= 1) s += __shfl_xor(s, o);
  float inv = 1.f / s;
  float* o0 = outT + (i64)b * 128 * 512 + m;
  o0[(i64)lane * 512]        = e0 * inv;
  o0[(i64)(lane + 64) * 512] = e1 * inv;
}

// softmax over P rows (128 cols) with 1/TEMP scaling, in place
__global__ void softmax_P(float* __restrict__ P) {
  int gw = (int)((blockIdx.x * (i64)blockDim.x + threadIdx.x) >> 6);
  int lane = threadIdx.x & 63;
  if (gw >= 32 * 3 * 1024) return;
  float* p = P + (i64)gw * 128;
  float x0 = p[lane] * TEMP_ISQ, x1 = p[lane + 64] * TEMP_ISQ;
  float mx = fmaxf(x0, x1);
  #pragma unroll
  for (int o = 32; o; o >>= 1) mx = fmaxf(mx, __shfl_xor(mx, o));
  float e0 = expf(x0 - mx), e1 = expf(x1 - mx);
  float s = e0 + e1;
  #pragma unroll
  for (int o = 32; o; o >>= 1) s += __shfl_xor(s, o);
  float inv = 1.f / s;
  p[lane]      = e0 * inv;
  p[lane + 64] = e1 * inv;
}

// emomean[b,e] = mean_l emo[b,l,e]
__global__ void colmean_kernel(const float* __restrict__ emo, float* __restrict__ emomean) {
  int b = blockIdx.y;
  int e = blockIdx.x * 256 + threadIdx.x;
  const float* p = emo + (i64)b * 1024 * 1024 + e;
  float s = 0.f;
  for (int l = 0; l < 1024; ++l) s += p[(i64)l * 1024];
  emomean[b * 1024 + e] = s * (1.f / 1024.f);
}

// Apool[b,k] = dot(emomean[b,:], agg[b,k,:])
__global__ void apool_kernel(const float* __restrict__ emomean, const float* __restrict__ agg,
                             float* __restrict__ Apool) {
  int gw = (int)((blockIdx.x * (i64)blockDim.x + threadIdx.x) >> 6);
  int lane = threadIdx.x & 63;
  if (gw >= 32 * 128) return;
  int b = gw >> 7, k = gw & 127;
  const float* ag = agg + ((i64)b * 128 + k) * 1024;
  const float* em = emomean + (i64)b * 1024;
  float s = 0.f;
  #pragma unroll
  for (int j = 0; j < 16; ++j) { int e = j * 64 + lane; s += em[e] * ag[e]; }
  #pragma unroll
  for (int o = 32; o; o >>= 1) s += __shfl_down(s, o);
  if (!lane) Apool[gw] = s;
}

// route[b,e] = sum_k Apool[b,k]*agg[b,k,e]
__global__ void route_kernel(const float* __restrict__ Apool, const float* __restrict__ agg,
                             float* __restrict__ route) {
  int b = blockIdx.y;
  int e = blockIdx.x * 256 + threadIdx.x;
  __shared__ float Ap[128];
  if (threadIdx.x < 128) Ap[threadIdx.x] = Apool[b * 128 + threadIdx.x];
  __syncthreads();
  const float* ag = agg + (i64)b * 128 * 1024 + e;
  float s = 0.f;
  for (int k = 0; k < 128; ++k) s += Ap[k] * ag[(i64)k * 1024];
  route[b * 1024 + e] = s;
}

// rb[b] = dot(route[b,:], ele_W[1024:2048]) + ele_b
__global__ void rb_kernel(const float* __restrict__ route, const float* __restrict__ eleW,
                          const float* __restrict__ eleb, float* __restrict__ rb) {
  int b = blockIdx.x, t = threadIdx.x;
  float s = 0.f;
  for (int j = t; j < 1024; j += 256) s += route[b * 1024 + j] * eleW[1024 + j];
  __shared__ float red[256];
  red[t] = s; __syncthreads();
  for (int o = 128; o > 0; o >>= 1) { if (t < o) red[t] += red[t + o]; __syncthreads(); }
  if (t == 0) rb[b] = red[0] + eleb[0];
}

// Re[b,l] = tanh(dot(emo[b,l,:], ele_W[0:1024]) + rb[b])
__global__ void re_kernel(const float* __restrict__ emo, const float* __restrict__ eleW,
                          const float* __restrict__ rb, float* __restrict__ Re) {
  int gw = (int)((blockIdx.x * (i64)blockDim.x + threadIdx.x) >> 6);
  int lane = threadIdx.x & 63;
  if (gw >= 32 * 1024) return;
  int b = gw >> 10;
  const float* p = emo + (i64)gw * 1024;
  float s = 0.f;
  #pragma unroll
  for (int j = 0; j < 16; ++j) { int e = j * 64 + lane; s += p[e] * eleW[e]; }
  #pragma unroll
  for (int o = 32; o; o >>= 1) s += __shfl_down(s, o);
  if (!lane) Re[gw] = tanhf(s + rb[b]);
}

// Pmean two-stage (deterministic): Ppart[bi,c,k] = sum over 128 l
__global__ void pmean1_kernel(const float* __restrict__ P, float* __restrict__ Ppart) {
  int bi = blockIdx.x;   // 0..95 (b*3+i)
  int c  = blockIdx.y;   // 0..7
  int k  = threadIdx.x;  // 0..127
  const float* p = P + ((i64)bi * 1024 + c * 128) * 128 + k;
  float s = 0.f;
  for (int l = 0; l < 128; ++l) s += p[(i64)l * 128];
  Ppart[((i64)bi * 8 + c) * 128 + k] = s;
}
__global__ void pmean2_kernel(const float* __restrict__ Ppart, float* __restrict__ Pmean) {
  int bi = blockIdx.x, k = threadIdx.x;
  float s = 0.f;
  #pragma unroll
  for (int c = 0; c < 8; ++c) s += Ppart[((i64)bi * 8 + c) * 128 + k];
  Pmean[bi * 128 + k] = s * (1.f / 1024.f);
}

// O[b,i,l,h] = tanh( (1/3) * sum_k P[b,i,l,k] * V[b,k,h] )
__global__ __launch_bounds__(256)
void ov_kernel(const float* __restrict__ P, const float* __restrict__ V, float* __restrict__ O) {
  int b = blockIdx.z, i = blockIdx.y, lt = blockIdx.x * 64;
  __shared__ float Ps[64 * 128];   // 32 KB
  __shared__ float Vs[128 * 28];   // 14 KB
  int t = threadIdx.x;
  const float* psrc = P + ((i64)(b * 3 + i) * 1024 + lt) * 128;
  #pragma unroll
  for (int s = 0; s < 32; ++s) Ps[t + 256 * s] = psrc[t + 256 * s];
  const float* vsrc = V + (i64)b * 128 * 28;
  #pragma unroll
  for (int s = 0; s < 14; ++s) Vs[t + 256 * s] = vsrc[t + 256 * s];
  __syncthreads();
  #pragma unroll
  for (int s = 0; s < 7; ++s) {
    int o = t + 256 * s;            // 64*28 = 1792 = 256*7
    int l = o / 28, h = o - l * 28;
    float acc = 0.f;
    for (int k = 0; k < 128; ++k) acc += Ps[l * 128 + k] * Vs[k * 28 + h];
    O[((i64)(b * 3 + i) * 1024 + lt + l) * 28 + h] = tanhf(acc * (1.f / 3.f));
  }
}

// Rdiag[b,i] = sum_k Pmean[b,i,k]*Rp[b,k,i]; gate = softmax_i(Rdiag)
__global__ void rdiag_gate_kernel(const float* __restrict__ Pmean, const float* __restrict__ Rp,
                                  float* __restrict__ gate) {
  int b = blockIdx.x, t = threadIdx.x;  // 128 threads
  __shared__ float red[128];
  __shared__ float rd[3];
  for (int i = 0; i < 3; ++i) {
    float v = Pmean[((i64)b * 3 + i) * 128 + t] * Rp[(i64)b * 384 + t * 3 + i];
    red[t] = v; __syncthreads();
    for (int o = 64; o > 0; o >>= 1) { if (t < o) red[t] += red[t + o]; __syncthreads(); }
    if (t == 0) rd[i] = red[0];
    __syncthreads();
  }
  if (t == 0) {
    float m = fmaxf(rd[0], fmaxf(rd[1], rd[2]));
    float e0 = expf(rd[0] - m), e1 = expf(rd[1] - m), e2 = expf(rd[2] - m);
    float inv = 1.f / (e0 + e1 + e2);
    gate[b * 3 + 0] = e0 * inv; gate[b * 3 + 1] = e1 * inv; gate[b * 3 + 2] = e2 * inv;
  }
}

// out[b,l,e] = emo * (1 + Re[b,l] * sum_i gate_i * O[b,i,l,h_i(e)])
__global__ __launch_bounds__(256)
void final_kernel(const float* __restrict__ emo, const float* __restrict__ Re,
                  const float* __restrict__ O, const float* __restrict__ gate,
                  float* __restrict__ out) {
  i64 bl = blockIdx.x;                 // b*1024 + l
  int b = (int)(bl >> 10), l = (int)(bl & 1023);
  __shared__ float Gg[16];
  int t = threadIdx.x;
  if (t < 16) {
    float g0 = gate[b * 3], g1 = gate[b * 3 + 1], g2 = gate[b * 3 + 2];
    float o0 = O[((i64)(b * 3 + 0) * 1024 + l) * 28 + (t >> 2)];
    float o1 = O[((i64)(b * 3 + 1) * 1024 + l) * 28 + 4 + (t >> 1)];
    float o2 = O[((i64)(b * 3 + 2) * 1024 + l) * 28 + 12 + t];
    Gg[t] = g0 * o0 + g1 * o1 + g2 * o2;
  }
  __syncthreads();
  float re = Re[bl];
  const float4* ep = (const float4*)(emo + bl * 1024);
  float4* op = (float4*)(out + bl * 1024);
  float4 e4 = ep[t];
  float g = 1.f + re * Gg[t >> 4];     // e = t*4 -> group e>>6 = t>>4
  op[t] = make_float4(e4.x * g, e4.y * g, e4.z * g, e4.w * g);
}

// ---------------- launcher ----------------
extern "C" void kernel_launch(void* const* d_in, const int* in_sizes, int n_in,
                              void* d_out, int out_size, void* d_ws, size_t ws_size,
                              hipStream_t stream) {
  const float* emo     = (const float*)d_in[0];
  const float* phr     = (const float*)d_in[1];
  const float* video   = (const float*)d_in[2];
  const float* w_v_W   = (const float*)d_in[3];
  const float* w_v_b   = (const float*)d_in[4];
  const float* agg_a_W = (const float*)d_in[5];
  const float* agg_a_b = (const float*)d_in[6];
  const float* agg_c_W = (const float*)d_in[7];
  const float* agg_c_b = (const float*)d_in[8];
  const float* ele_W   = (const float*)d_in[9];
  const float* ele_b   = (const float*)d_in[10];
  const float* wq_W    = (const float*)d_in[11];
  const float* wq_b    = (const float*)d_in[12];
  const float* wk_W    = (const float*)d_in[13];
  const float* wk_b    = (const float*)d_in[14];
  const float* wv_W    = (const float*)d_in[15];
  const float* wv_b    = (const float*)d_in[16];
  const float* wr_W    = (const float*)d_in[17];
  const float* wr_b    = (const float*)d_in[18];

  float* wsf = (float*)d_ws;
  size_t off = 0;
  auto alloc = [&](size_t elems) { size_t o = off; off += (elems + 63) & ~(size_t)63; return o; };
  size_t oCombine = alloc(16777216);  // [B,512,1024]  (reused by P [B,3,1024,128])
  size_t oC       = alloc(16777216);  // [B,512,1024]  (reused by Q [B,1024,448])
  size_t oLogitsA = alloc(2097152);   // [B,512,128]
  size_t oAttnAT  = alloc(2097152);   // [B,128,512]
  size_t oAgg     = alloc(4194304);   // [B,128,1024]
  size_t oKpT     = alloc(1835008);   // [B,448,128]
  size_t oV       = alloc(114688);    // [B,128,28]
  size_t oRp      = alloc(12288);     // [B,128,3]
  size_t oO       = alloc(2752512);   // [B,3,1024,28]
  size_t oEmomean = alloc(32768);
  size_t oApool   = alloc(4096);
  size_t oRoute   = alloc(32768);
  size_t oRb      = alloc(32);
  size_t oRe      = alloc(32768);
  size_t oPpart   = alloc(98304);     // [96,8,128]
  size_t oPmean   = alloc(12288);     // [96,128]
  size_t oGate    = alloc(96);

  float* combine = wsf + oCombine;
  float* Cbuf    = wsf + oC;
  float* logitsA = wsf + oLogitsA;
  float* attnAT  = wsf + oAttnAT;
  float* agg     = wsf + oAgg;
  float* KpT     = wsf + oKpT;
  float* Vb      = wsf + oV;
  float* Rpb     = wsf + oRp;
  float* Obuf    = wsf + oO;
  float* emomean = wsf + oEmomean;
  float* Apool   = wsf + oApool;
  float* route   = wsf + oRoute;
  float* rbv     = wsf + oRb;
  float* Re      = wsf + oRe;
  float* Ppart   = wsf + oPpart;
  float* Pmean   = wsf + oPmean;
  float* gate    = wsf + oGate;
  float* Q = Cbuf;      // reuse (C dead after G4)
  float* P = combine;   // reuse (combine dead after G3)

  dim3 blk(256);

  // combine rows 256..511 = video
  vcopy_kernel<<<8192, blk, 0, stream>>>(video, combine);
  // G1: pooled phr @ w_v_W + b -> combine rows 0..255
  gemm_f32<1,0><<<dim3(16,4,32), blk, 0, stream>>>(phr, (i64)512*1024, w_v_W, 0, w_v_b,
      combine, (i64)512*1024, 256, 1024, 1024, 1024, 1024, 1024, nullptr);
  // G2: combine @ agg_a_W + b -> logitsA
  gemm_f32<0,0><<<dim3(2,8,32), blk, 0, stream>>>(combine, (i64)512*1024, agg_a_W, 0, agg_a_b,
      logitsA, (i64)512*128, 512, 1024, 128, 1024, 128, 128, nullptr);
  softmax_attn_a<<<4096, blk, 0, stream>>>(logitsA, attnAT);
  // G3: combine @ agg_c_W + b -> C
  gemm_f32<0,0><<<dim3(16,8,32), blk, 0, stream>>>(combine, (i64)512*1024, agg_c_W, 0, agg_c_b,
      Cbuf, (i64)512*1024, 512, 1024, 1024, 1024, 1024, 1024, nullptr);
  // G4: attn_a^T @ C -> agg_feat
  gemm_f32<0,0><<<dim3(16,2,32), blk, 0, stream>>>(attnAT, (i64)128*512, Cbuf, (i64)512*1024, nullptr,
      agg, (i64)128*1024, 128, 512, 1024, 512, 1024, 1024, nullptr);

  // element routing
  colmean_kernel<<<dim3(4,32), blk, 0, stream>>>(emo, emomean);
  apool_kernel<<<1024, blk, 0, stream>>>(emomean, agg, Apool);
  route_kernel<<<dim3(4,32), blk, 0, stream>>>(Apool, agg, route);
  rb_kernel<<<32, blk, 0, stream>>>(route, ele_W, ele_b, rbv);
  re_kernel<<<8192, blk, 0, stream>>>(emo, ele_W, rbv, Re);

  // K (transposed out), V, R projections of agg_feat
  gemm_f32<0,1><<<dim3(7,2,32), blk, 0, stream>>>(agg, (i64)128*1024, wk_W, 0, wk_b,
      KpT, (i64)448*128, 128, 1024, 448, 1024, 448, 128, nullptr);
  gemm_f32<0,0><<<dim3(1,2,32), blk, 0, stream>>>(agg, (i64)128*1024, wv_W, 0, wv_b,
      Vb, (i64)128*28, 128, 1024, 28, 1024, 28, 28, nullptr);
  gemm_f32<0,0><<<dim3(1,2,32), blk, 0, stream>>>(agg, (i64)128*1024, wr_W, 0, wr_b,
      Rpb, (i64)128*3, 128, 1024, 3, 1024, 3, 3, nullptr);

  // G6: (Re*emo) @ wq_W + b -> Q
  gemm_f32<2,0><<<dim3(7,16,32), blk, 0, stream>>>(emo, (i64)1024*1024, wq_W, 0, wq_b,
      Q, (i64)1024*448, 1024, 1024, 448, 1024, 448, 448, Re);

  // G8: per-subspace S_i = Q_block @ KpT_block -> P logits
  const int doffs[3] = {0, 256, 384};
  const int kds[3]   = {256, 128, 64};
  for (int i = 0; i < 3; ++i) {
    gemm_f32<0,0><<<dim3(2,16,32), blk, 0, stream>>>(Q + doffs[i], (i64)1024*448,
        KpT + (i64)doffs[i]*128, (i64)448*128, nullptr,
        P + (i64)i*1024*128, (i64)3*1024*128, 1024, kds[i], 128, 448, 128, 128, nullptr);
  }
  softmax_P<<<24576, blk, 0, stream>>>(P);
  pmean1_kernel<<<dim3(96,8), 128, 0, stream>>>(P, Ppart);
  pmean2_kernel<<<96, 128, 0, stream>>>(Ppart, Pmean);
  ov_kernel<<<dim3(16,3,32), blk, 0, stream>>>(P, Vb, Obuf);
  rdiag_gate_kernel<<<32, 128, 0, stream>>>(Pmean, Rpb, gate);
  final_kernel<<<32768, blk, 0, stream>>>(emo, Re, Obuf, gate, (float*)d_out);
}

// Round 2
// 578.907 us; speedup vs baseline: 4.0544x; 4.0544x over previous
//
#include <hip/hip_runtime.h>
#include <math.h>

typedef long long i64;
typedef __attribute__((ext_vector_type(8))) short bf16x8;
typedef __attribute__((ext_vector_type(4))) float f32x4;

#define TEMP_ISQ 0.047245559f   // 1/sqrt(448)

__device__ __forceinline__ unsigned short f2b(float x) {
  union { float f; unsigned u; } a; a.f = x;
  return (unsigned short)((a.u + 0x7fffu + ((a.u >> 16) & 1u)) >> 16);
}
__device__ __forceinline__ float b2f(unsigned short b) {
  union { float f; unsigned u; } a; a.u = ((unsigned)b) << 16; return a.f;
}

// ================= NT bf16 MFMA GEMM =================
// out[M,N] = A[M,K] @ BT[N,K]^T (+bias). 128x128 tile, BK=32, 4 waves.
// BIAS: 0 none, 1 col bias[col], 2 row bias[row]
// OUTM: 0 fp32, 1 bf16, 2 both (Ob fp32 + O2b bf16)
// Requirements: M % 128 == 0, K % 32 == 0, BT buffer padded to gridDim.x*128 rows.
template<int BIAS, int OUTM>
__global__ __launch_bounds__(256)
void gemm_mfma(const unsigned short* __restrict__ Ab, i64 sA,
               const unsigned short* __restrict__ Bb, i64 sB,
               const float* __restrict__ bias,
               void* __restrict__ Ob, i64 sO,
               unsigned short* __restrict__ O2b, i64 sO2,
               int Nn, int Kd, int ldA, int ldB, int ldO)
{
  __shared__ unsigned short As[4096];   // 128 rows x 32 cols bf16 (8KB)
  __shared__ unsigned short Bs[4096];
  const int tid = threadIdx.x;
  const int w = tid >> 6, lane = tid & 63;
  const int z = blockIdx.z;
  const int m0 = blockIdx.y * 128, n0 = blockIdx.x * 128;
  const unsigned short* A = Ab + (i64)z * sA;
  const unsigned short* B = Bb + (i64)z * sB;
  const int wr = w >> 1, wc = w & 1;
  const int r0 = tid >> 2, s0 = tid & 3;
  const int cL = lane & 15, sl = lane >> 4;

  f32x4 acc[4][4];
  #pragma unroll
  for (int i = 0; i < 4; ++i)
    #pragma unroll
    for (int j = 0; j < 4; ++j) acc[i][j] = (f32x4){0.f, 0.f, 0.f, 0.f};

  for (int k0 = 0; k0 < Kd; k0 += 32) {
    // stage A,B tiles: linear LDS dest, pre-swizzled global source (slot ^= (row>>1)&3)
    #pragma unroll
    for (int q = 0; q < 2; ++q) {
      int r = r0 + q * 64;
      int sg = s0 ^ ((r >> 1) & 3);
      const unsigned short* sa = A + (i64)(m0 + r) * ldA + k0 + sg * 8;
      const unsigned short* sb = B + (i64)(n0 + r) * ldB + k0 + sg * 8;
      __builtin_amdgcn_global_load_lds(
          (__attribute__((address_space(1))) void*)sa,
          (__attribute__((address_space(3))) void*)&As[(q * 256 + w * 64) * 8], 16, 0, 0);
      __builtin_amdgcn_global_load_lds(
          (__attribute__((address_space(1))) void*)sb,
          (__attribute__((address_space(3))) void*)&Bs[(q * 256 + w * 64) * 8], 16, 0, 0);
    }
    __syncthreads();
    bf16x8 af[4], bfv[4];
    #pragma unroll
    for (int mi = 0; mi < 4; ++mi) {
      int rr = wr * 64 + mi * 16 + cL;
      int se = sl ^ ((rr >> 1) & 3);
      af[mi] = *(const bf16x8*)&As[rr * 32 + se * 8];
    }
    #pragma unroll
    for (int ni = 0; ni < 4; ++ni) {
      int rr = wc * 64 + ni * 16 + cL;
      int se = sl ^ ((rr >> 1) & 3);
      bfv[ni] = *(const bf16x8*)&Bs[rr * 32 + se * 8];
    }
    #pragma unroll
    for (int mi = 0; mi < 4; ++mi)
      #pragma unroll
      for (int ni = 0; ni < 4; ++ni)
        acc[mi][ni] = __builtin_amdgcn_mfma_f32_16x16x32_bf16(af[mi], bfv[ni], acc[mi][ni], 0, 0, 0);
    __syncthreads();
  }

  // epilogue: D layout col=lane&15, row=(lane>>4)*4+reg  [m89]
  #pragma unroll
  for (int mi = 0; mi < 4; ++mi) {
    const int rowb = m0 + wr * 64 + mi * 16 + sl * 4;
    #pragma unroll
    for (int ni = 0; ni < 4; ++ni) {
      const int col = n0 + wc * 64 + ni * 16 + cL;
      if (col < Nn) {
        float bc = (BIAS == 1) ? bias[col] : 0.f;
        #pragma unroll
        for (int rg = 0; rg < 4; ++rg) {
          float v = acc[mi][ni][rg] + bc;
          if (BIAS == 2) v += bias[rowb + rg];
          i64 oidx = (i64)(rowb + rg) * ldO + col;
          if (OUTM == 0)      ((float*)Ob)[(i64)z * sO + oidx] = v;
          else if (OUTM == 1) ((unsigned short*)Ob)[(i64)z * sO + oidx] = f2b(v);
          else {
            ((float*)Ob)[(i64)z * sO + oidx] = v;
            O2b[(i64)z * sO2 + oidx] = f2b(v);
          }
        }
      }
    }
  }
}

// ================= prep kernels =================

// weight transpose+convert: out[n][k] = bf16(in[k][n]) for n<N, 0 for N<=n<Npad. ldOut=Kd.
__global__ __launch_bounds__(256)
void transpose_w(const float* __restrict__ in, unsigned short* __restrict__ out,
                 int Kd, int N, int Npad) {
  __shared__ float T[32][33];
  int n0 = blockIdx.x * 32, k0 = blockIdx.y * 32;
  int t = threadIdx.x;
  #pragma unroll
  for (int p = 0; p < 4; ++p) {
    int idx = t + 256 * p; int kk = idx >> 5, nn = idx & 31;
    float v = 0.f;
    if (n0 + nn < N && k0 + kk < Kd) v = in[(i64)(k0 + kk) * N + (n0 + nn)];
    T[nn][kk] = v;
  }
  __syncthreads();
  #pragma unroll
  for (int p = 0; p < 4; ++p) {
    int idx = t + 256 * p; int nn = idx >> 5, kk = idx & 31;
    if (n0 + nn < Npad && k0 + kk < Kd) out[(i64)(n0 + nn) * Kd + (k0 + kk)] = f2b(T[nn][kk]);
  }
}

__global__ void kvr_bias_kernel(const float* wkb, const float* wvb, const float* wrb, float* out) {
  int t = blockIdx.x * 256 + threadIdx.x;
  if (t >= 480) return;
  out[t] = (t < 448) ? wkb[t] : (t < 476) ? wvb[t - 448] : (t < 479) ? wrb[t - 476] : 0.f;
}

// pooled phr -> bf16 [B,256,1024]
__global__ void pool_phr(const float* __restrict__ phr, unsigned short* __restrict__ out) {
  i64 idx = (i64)blockIdx.x * 256 + threadIdx.x;   // ushort4 index, total 2M
  if (idx >= 2097152) return;
  i64 bm = idx >> 8; int c = (int)(idx & 255);
  i64 b = bm >> 8, m = bm & 255;
  const float4* r0 = (const float4*)(phr + (b * 512 + 2 * m) * 1024) + c;
  const float4* r1 = (const float4*)(phr + (b * 512 + 2 * m + 1) * 1024) + c;
  float4 a = *r0, d = *r1;
  ushort4 o;
  o.x = f2b(0.5f * (a.x + d.x)); o.y = f2b(0.5f * (a.y + d.y));
  o.z = f2b(0.5f * (a.z + d.z)); o.w = f2b(0.5f * (a.w + d.w));
  ((ushort4*)out)[idx] = o;
}

// video -> bf16 combine rows 256..511
__global__ void vconv(const float* __restrict__ video, unsigned short* __restrict__ combine) {
  i64 idx = (i64)blockIdx.x * 256 + threadIdx.x;   // float4/ushort4 index, total 2M
  if (idx >= 2097152) return;
  i64 b = idx >> 16, r = idx & 65535;              // 256*1024/4 = 65536 chunks/batch
  float4 v = ((const float4*)video)[idx];
  ushort4 o;
  o.x = f2b(v.x); o.y = f2b(v.y); o.z = f2b(v.z); o.w = f2b(v.w);
  ((ushort4*)combine)[b * 131072 + 65536 + r] = o;
}

// ================= softmax / routing =================

__global__ void softmax_attn_a(const float* __restrict__ logits, unsigned short* __restrict__ outT) {
  int gw = (int)(((i64)blockIdx.x * blockDim.x + threadIdx.x) >> 6);
  int lane = threadIdx.x & 63;
  if (gw >= 32 * 512) return;
  int b = gw >> 9, m = gw & 511;
  const float* p = logits + (i64)gw * 128;
  float x0 = p[lane], x1 = p[lane + 64];
  float mx = fmaxf(x0, x1);
  #pragma unroll
  for (int o = 32; o; o >>= 1) mx = fmaxf(mx, __shfl_xor(mx, o));
  float e0 = expf(x0 - mx), e1 = expf(x1 - mx);
  float s = e0 + e1;
  #pragma unroll
  for (int o = 32; o; o >>= 1) s += __shfl_xor(s, o);
  float inv = 1.f / s;
  unsigned short* o0 = outT + (i64)b * 128 * 512 + m;
  o0[(i64)lane * 512] = f2b(e0 * inv);
  o0[(i64)(lane + 64) * 512] = f2b(e1 * inv);
}

__global__ void softmax_P_bf(const float* __restrict__ PL, unsigned short* __restrict__ P) {
  i64 gw = ((i64)blockIdx.x * blockDim.x + threadIdx.x) >> 6;
  int lane = threadIdx.x & 63;
  if (gw >= 98304) return;
  const float* p = PL + gw * 128;
  float x0 = p[lane] * TEMP_ISQ, x1 = p[lane + 64] * TEMP_ISQ;
  float mx = fmaxf(x0, x1);
  #pragma unroll
  for (int o = 32; o; o >>= 1) mx = fmaxf(mx, __shfl_xor(mx, o));
  float e0 = expf(x0 - mx), e1 = expf(x1 - mx);
  float s = e0 + e1;
  #pragma unroll
  for (int o = 32; o; o >>= 1) s += __shfl_xor(s, o);
  float inv = 1.f / s;
  P[gw * 128 + lane] = f2b(e0 * inv);
  P[gw * 128 + lane + 64] = f2b(e1 * inv);
}

__global__ void colmean_kernel(const float* __restrict__ emo, float* __restrict__ emomean) {
  int b = blockIdx.y;
  int e = blockIdx.x * 256 + threadIdx.x;
  const float* p = emo + (i64)b * 1024 * 1024 + e;
  float s = 0.f;
  for (int l = 0; l < 1024; ++l) s += p[(i64)l * 1024];
  emomean[b * 1024 + e] = s * (1.f / 1024.f);
}

__global__ void apool_kernel(const float* __restrict__ emomean, const float* __restrict__ agg,
                             float* __restrict__ Apool) {
  int gw = (int)(((i64)blockIdx.x * blockDim.x + threadIdx.x) >> 6);
  int lane = threadIdx.x & 63;
  if (gw >= 32 * 128) return;
  int b = gw >> 7, k = gw & 127;
  const float* ag = agg + ((i64)b * 128 + k) * 1024;
  const float* em = emomean + (i64)b * 1024;
  float s = 0.f;
  #pragma unroll
  for (int j = 0; j < 16; ++j) { int e = j * 64 + lane; s += em[e] * ag[e]; }
  #pragma unroll
  for (int o = 32; o; o >>= 1) s += __shfl_down(s, o);
  if (!lane) Apool[gw] = s;
}

__global__ void route_kernel(const float* __restrict__ Apool, const float* __restrict__ agg,
                             float* __restrict__ route) {
  int b = blockIdx.y;
  int e = blockIdx.x * 256 + threadIdx.x;
  __shared__ float Ap[128];
  if (threadIdx.x < 128) Ap[threadIdx.x] = Apool[b * 128 + threadIdx.x];
  __syncthreads();
  const float* ag = agg + (i64)b * 128 * 1024 + e;
  float s = 0.f;
  for (int k = 0; k < 128; ++k) s += Ap[k] * ag[(i64)k * 1024];
  route[b * 1024 + e] = s;
}

__global__ void rb_kernel(const float* __restrict__ route, const float* __restrict__ eleW,
                          const float* __restrict__ eleb, float* __restrict__ rb) {
  int b = blockIdx.x, t = threadIdx.x;
  float s = 0.f;
  for (int j = t; j < 1024; j += 256) s += route[b * 1024 + j] * eleW[1024 + j];
  __shared__ float red[256];
  red[t] = s; __syncthreads();
  for (int o = 128; o > 0; o >>= 1) { if (t < o) red[t] += red[t + o]; __syncthreads(); }
  if (t == 0) rb[b] = red[0] + eleb[0];
}

// fused: Re = tanh(emo_row . eleW[0:1024] + rb[b]); remo = bf16(Re * emo_row)
__global__ __launch_bounds__(256)
void re_scale_kernel(const float* __restrict__ emo, const float* __restrict__ eleW,
                     const float* __restrict__ rb, float* __restrict__ Re,
                     unsigned short* __restrict__ remo) {
  i64 bl = blockIdx.x;
  int b = (int)(bl >> 10);
  int t = threadIdx.x, lane = t & 63, w = t >> 6;
  float4 e4 = ((const float4*)(emo + bl * 1024))[t];
  float4 w4 = ((const float4*)eleW)[t];
  float s = e4.x * w4.x + e4.y * w4.y + e4.z * w4.z + e4.w * w4.w;
  #pragma unroll
  for (int o = 32; o; o >>= 1) s += __shfl_xor(s, o);
  __shared__ float wsum[4];
  if (!lane) wsum[w] = s;
  __syncthreads();
  float re = tanhf(wsum[0] + wsum[1] + wsum[2] + wsum[3] + rb[b]);
  if (t == 0) Re[bl] = re;
  ushort4 o4;
  o4.x = f2b(e4.x * re); o4.y = f2b(e4.y * re);
  o4.z = f2b(e4.z * re); o4.w = f2b(e4.w * re);
  ((ushort4*)remo)[bl * 256 + t] = o4;
}

// ================= P consumers =================

__global__ void pmean1_kernel(const unsigned short* __restrict__ P, float* __restrict__ Ppart) {
  int bi = blockIdx.x, c = blockIdx.y, k = threadIdx.x;
  const unsigned short* p = P + ((i64)bi * 1024 + c * 128) * 128 + k;
  float s = 0.f;
  for (int l = 0; l < 128; ++l) s += b2f(p[(i64)l * 128]);
  Ppart[((i64)bi * 8 + c) * 128 + k] = s;
}
__global__ void pmean2_kernel(const float* __restrict__ Ppart, float* __restrict__ Pmean) {
  int bi = blockIdx.x, k = threadIdx.x;
  float s = 0.f;
  #pragma unroll
  for (int c = 0; c < 8; ++c) s += Ppart[((i64)bi * 8 + c) * 128 + k];
  Pmean[bi * 128 + k] = s * (1.f / 1024.f);
}

// O[b,i,l,h] = tanh((1/3) * sum_k P[b,i,l,k] * V[b,k,h]); V from KVR cols 448..475
__global__ __launch_bounds__(256)
void ov_kernel(const unsigned short* __restrict__ P, const unsigned short* __restrict__ KVR,
               float* __restrict__ O) {
  int b = blockIdx.z, i = blockIdx.y, lt = blockIdx.x * 64;
  __shared__ float Ps[64 * 128];
  __shared__ float Vs[128 * 28];
  int t = threadIdx.x;
  const unsigned short* psrc = P + ((i64)(b * 3 + i) * 1024 + lt) * 128;
  #pragma unroll
  for (int s = 0; s < 32; ++s) Ps[t + 256 * s] = b2f(psrc[t + 256 * s]);
  const unsigned short* vsrc = KVR + (i64)b * 61440;
  #pragma unroll
  for (int s = 0; s < 14; ++s) {
    int idx = t + 256 * s;
    int k = idx / 28, h = idx - k * 28;
    Vs[idx] = b2f(vsrc[(i64)k * 480 + 448 + h]);
  }
  __syncthreads();
  #pragma unroll
  for (int s = 0; s < 7; ++s) {
    int o = t + 256 * s;
    int l = o / 28, h = o - l * 28;
    float acc = 0.f;
    for (int k = 0; k < 128; ++k) acc += Ps[l * 128 + k] * Vs[k * 28 + h];
    O[((i64)(b * 3 + i) * 1024 + lt + l) * 28 + h] = tanhf(acc * (1.f / 3.f));
  }
}

__global__ void rdiag_gate_kernel(const float* __restrict__ Pmean, const unsigned short* __restrict__ KVR,
                                  float* __restrict__ gate) {
  int b = blockIdx.x, t = threadIdx.x;  // 128 threads
  __shared__ float red[128];
  __shared__ float rd[3];
  for (int i = 0; i < 3; ++i) {
    float v = Pmean[((i64)b * 3 + i) * 128 + t] * b2f(KVR[(i64)b * 61440 + t * 480 + 476 + i]);
    red[t] = v; __syncthreads();
    for (int o = 64; o > 0; o >>= 1) { if (t < o) red[t] += red[t + o]; __syncthreads(); }
    if (t == 0) rd[i] = red[0];
    __syncthreads();
  }
  if (t == 0) {
    float m = fmaxf(rd[0], fmaxf(rd[1], rd[2]));
    float e0 = expf(rd[0] - m), e1 = expf(rd[1] - m), e2 = expf(rd[2] - m);
    float inv = 1.f / (e0 + e1 + e2);
    gate[b * 3 + 0] = e0 * inv; gate[b * 3 + 1] = e1 * inv; gate[b * 3 + 2] = e2 * inv;
  }
}

__global__ __launch_bounds__(256)
void final_kernel(const float* __restrict__ emo, const float* __restrict__ Re,
                  const float* __restrict__ O, const float* __restrict__ gate,
                  float* __restrict__ out) {
  i64 bl = blockIdx.x;
  int b = (int)(bl >> 10), l = (int)(bl & 1023);
  __shared__ float Gg[16];
  int t = threadIdx.x;
  if (t < 16) {
    float g0 = gate[b * 3], g1 = gate[b * 3 + 1], g2 = gate[b * 3 + 2];
    float o0 = O[((i64)(b * 3 + 0) * 1024 + l) * 28 + (t >> 2)];
    float o1 = O[((i64)(b * 3 + 1) * 1024 + l) * 28 + 4 + (t >> 1)];
    float o2 = O[((i64)(b * 3 + 2) * 1024 + l) * 28 + 12 + t];
    Gg[t] = g0 * o0 + g1 * o1 + g2 * o2;
  }
  __syncthreads();
  float re = Re[bl];
  float4 e4 = ((const float4*)(emo + bl * 1024))[t];
  float g = 1.f + re * Gg[t >> 4];
  ((float4*)(out + bl * 1024))[t] = make_float4(e4.x * g, e4.y * g, e4.z * g, e4.w * g);
}

// ================= launcher =================
extern "C" void kernel_launch(void* const* d_in, const int* in_sizes, int n_in,
                              void* d_out, int out_size, void* d_ws, size_t ws_size,
                              hipStream_t stream) {
  const float* emo     = (const float*)d_in[0];
  const float* phr     = (const float*)d_in[1];
  const float* video   = (const float*)d_in[2];
  const float* w_v_W   = (const float*)d_in[3];
  const float* w_v_b   = (const float*)d_in[4];
  const float* agg_a_W = (const float*)d_in[5];
  const float* agg_a_b = (const float*)d_in[6];
  const float* agg_c_W = (const float*)d_in[7];
  const float* agg_c_b = (const float*)d_in[8];
  const float* ele_W   = (const float*)d_in[9];
  const float* ele_b   = (const float*)d_in[10];
  const float* wq_W    = (const float*)d_in[11];
  const float* wq_b    = (const float*)d_in[12];
  const float* wk_W    = (const float*)d_in[13];
  const float* wk_b    = (const float*)d_in[14];
  const float* wv_W    = (const float*)d_in[15];
  const float* wv_b    = (const float*)d_in[16];
  const float* wr_W    = (const float*)d_in[17];
  const float* wr_b    = (const float*)d_in[18];

  char* ws = (char*)d_ws;
  // region map (bytes); overlays annotated
  const i64 oCombine = 0;            // ushort [32][512][1024]  (dead after G3')
  const i64 oPooled  = 33554432;     // ushort [32][256][1024] -> logitsA fp32 [32][512][128]
  const i64 oCT      = 50331648;     // ushort [32][1024][512]  (dead after G4)
  const i64 oRemo    = 0;            // ushort [32][1024][1024] overlay (written after G4)
  const i64 oPL      = 0;            // float  [96][1024][128]  overlay (written after G6)
  const i64 oAttnAT  = 83886080;     // ushort [32][128][512]
  const i64 oAggF    = 88080384;     // float  [32][128][1024]
  const i64 oAggB    = 104857600;    // ushort [32][128][1024]
  const i64 oP       = 88080384;     // ushort [96][1024][128]  overlay aggF+aggB (after KVR gemm)
  const i64 oQ       = 113246208;    // ushort [32][1024][448]
  const i64 oO       = 113246208;    // float  [32][3][1024][28] overlay Q (after G8)
  const i64 oWvT     = 142606336;    // ushort [1024][1024]
  const i64 oAaT     = 144703488;    // ushort [128][1024]
  const i64 oAcT     = 144965632;    // ushort [1024][1024]
  const i64 oWqT     = 147062784;    // ushort [512][1024] (rows 448..511 zero)
  const i64 oKvrT    = 148111360;    // ushort [512][1024] (448 wk / 28 wv / 3 wr / pad)
  const i64 oKVR     = 149159936;    // ushort [32][128][480]
  const i64 oKvrB    = 153092096;    // float [480]
  const i64 oEmomean = 153094144;
  const i64 oApool   = oEmomean + 131072;
  const i64 oRoute   = oApool + 16384;
  const i64 oRb      = oRoute + 131072;
  const i64 oRe      = oRb + 256;
  const i64 oPpart   = oRe + 131072;
  const i64 oPmean   = oPpart + 393216;
  const i64 oGate    = oPmean + 49152;

  unsigned short* combine = (unsigned short*)(ws + oCombine);
  unsigned short* pooled  = (unsigned short*)(ws + oPooled);
  float*          logitsA = (float*)(ws + oPooled);
  unsigned short* CT      = (unsigned short*)(ws + oCT);
  unsigned short* remo    = (unsigned short*)(ws + oRemo);
  float*          PL      = (float*)(ws + oPL);
  unsigned short* attnAT  = (unsigned short*)(ws + oAttnAT);
  float*          aggF    = (float*)(ws + oAggF);
  unsigned short* aggB    = (unsigned short*)(ws + oAggB);
  unsigned short* P       = (unsigned short*)(ws + oP);
  unsigned short* Q       = (unsigned short*)(ws + oQ);
  float*          O       = (float*)(ws + oO);
  unsigned short* wvT     = (unsigned short*)(ws + oWvT);
  unsigned short* aaT     = (unsigned short*)(ws + oAaT);
  unsigned short* acT     = (unsigned short*)(ws + oAcT);
  unsigned short* wqT     = (unsigned short*)(ws + oWqT);
  unsigned short* kvrT    = (unsigned short*)(ws + oKvrT);
  unsigned short* KVR     = (unsigned short*)(ws + oKVR);
  float*          kvrB    = (float*)(ws + oKvrB);
  float*          emomean = (float*)(ws + oEmomean);
  float*          Apool   = (float*)(ws + oApool);
  float*          route   = (float*)(ws + oRoute);
  float*          rbv     = (float*)(ws + oRb);
  float*          Re      = (float*)(ws + oRe);
  float*          Ppart   = (float*)(ws + oPpart);
  float*          Pmean   = (float*)(ws + oPmean);
  float*          gate    = (float*)(ws + oGate);

  dim3 blk(256);

  // weight prep
  transpose_w<<<dim3(32, 32), blk, 0, stream>>>(w_v_W, wvT, 1024, 1024, 1024);
  transpose_w<<<dim3(4, 32),  blk, 0, stream>>>(agg_a_W, aaT, 1024, 128, 128);
  transpose_w<<<dim3(32, 32), blk, 0, stream>>>(agg_c_W, acT, 1024, 1024, 1024);
  transpose_w<<<dim3(16, 32), blk, 0, stream>>>(wq_W, wqT, 1024, 448, 512);
  transpose_w<<<dim3(14, 32), blk, 0, stream>>>(wk_W, kvrT, 1024, 448, 448);
  transpose_w<<<dim3(1, 32),  blk, 0, stream>>>(wv_W, kvrT + (i64)448 * 1024, 1024, 28, 28);
  transpose_w<<<dim3(2, 32),  blk, 0, stream>>>(wr_W, kvrT + (i64)476 * 1024, 1024, 3, 36);
  kvr_bias_kernel<<<2, blk, 0, stream>>>(wk_b, wv_b, wr_b, kvrB);

  // feature aggregation
  pool_phr<<<8192, blk, 0, stream>>>(phr, pooled);
  vconv<<<8192, blk, 0, stream>>>(video, combine);
  // G1: combine[0:256] = pooled @ w_v + b
  gemm_mfma<1, 1><<<dim3(8, 2, 32), blk, 0, stream>>>(pooled, 262144, wvT, 0, w_v_b,
      (void*)combine, 524288, nullptr, 0, 1024, 1024, 1024, 1024, 1024);
  // G2: logitsA = combine @ agg_a + b
  gemm_mfma<1, 0><<<dim3(1, 4, 32), blk, 0, stream>>>(combine, 524288, aaT, 0, agg_a_b,
      (void*)logitsA, 65536, nullptr, 0, 128, 1024, 1024, 1024, 128);
  softmax_attn_a<<<4096, blk, 0, stream>>>(logitsA, attnAT);
  // G3': CT[e][m] = agg_cT @ combine^T + agg_c_b[e] (row bias)
  gemm_mfma<2, 1><<<dim3(4, 8, 32), blk, 0, stream>>>(acT, 0, combine, 524288, agg_c_b,
      (void*)CT, 524288, nullptr, 0, 512, 1024, 1024, 1024, 512);
  // G4: agg = attnAT @ CT^T (fp32 + bf16)
  gemm_mfma<0, 2><<<dim3(8, 1, 32), blk, 0, stream>>>(attnAT, 65536, CT, 524288, nullptr,
      (void*)aggF, 131072, aggB, 131072, 1024, 512, 512, 512, 1024);

  // element routing (fp32)
  colmean_kernel<<<dim3(4, 32), blk, 0, stream>>>(emo, emomean);
  apool_kernel<<<1024, blk, 0, stream>>>(emomean, aggF, Apool);
  route_kernel<<<dim3(4, 32), blk, 0, stream>>>(Apool, aggF, route);
  rb_kernel<<<32, blk, 0, stream>>>(route, ele_W, ele_b, rbv);
  re_scale_kernel<<<32768, blk, 0, stream>>>(emo, ele_W, rbv, Re, remo);

  // KVR = agg @ [wk|wv|wr] + bias (N=480 padded)
  gemm_mfma<1, 1><<<dim3(4, 1, 32), blk, 0, stream>>>(aggB, 131072, kvrT, 0, kvrB,
      (void*)KVR, 61440, nullptr, 0, 480, 1024, 1024, 1024, 480);
  // G6: Q = remo @ wq + b (N=448)
  gemm_mfma<1, 1><<<dim3(4, 8, 32), blk, 0, stream>>>(remo, 1048576, wqT, 0, wq_b,
      (void*)Q, 458752, nullptr, 0, 448, 1024, 1024, 1024, 448);

  // G8: per-subspace logits PL[i] = Q_blk @ Kp_blk^T
  const int doffs[3] = {0, 256, 384};
  const int kds[3]   = {256, 128, 64};
  for (int i = 0; i < 3; ++i) {
    gemm_mfma<0, 0><<<dim3(1, 8, 32), blk, 0, stream>>>(Q + doffs[i], 458752,
        KVR + doffs[i], 61440, nullptr,
        (void*)(PL + (i64)i * 131072), 393216, nullptr, 0, 128, kds[i], 448, 480, 128);
  }
  softmax_P_bf<<<24576, blk, 0, stream>>>(PL, P);
  pmean1_kernel<<<dim3(96, 8), 128, 0, stream>>>(P, Ppart);
  pmean2_kernel<<<96, 128, 0, stream>>>(Ppart, Pmean);
  ov_kernel<<<dim3(16, 3, 32), blk, 0, stream>>>(P, KVR, O);
  rdiag_gate_kernel<<<32, 128, 0, stream>>>(Pmean, KVR, gate);
  final_kernel<<<32768, blk, 0, stream>>>(emo, Re, O, gate, (float*)d_out);
}

// Round 3
// 521.732 us; speedup vs baseline: 4.4987x; 1.1096x over previous
//
#include <hip/hip_runtime.h>
#include <math.h>

typedef long long i64;
typedef __attribute__((ext_vector_type(8))) short bf16x8;
typedef __attribute__((ext_vector_type(4))) float f32x4;

#define TEMP_ISQ 0.047245559f   // 1/sqrt(448)

__device__ __forceinline__ unsigned short f2b(float x) {
  union { float f; unsigned u; } a; a.f = x;
  return (unsigned short)((a.u + 0x7fffu + ((a.u >> 16) & 1u)) >> 16);
}
__device__ __forceinline__ float b2f(unsigned short b) {
  union { float f; unsigned u; } a; a.u = ((unsigned)b) << 16; return a.f;
}

// ================= NT bf16 MFMA GEMM =================
// out[M,N] = A[M,K] @ BT[N,K]^T (+bias). 128x128 tile, BK=32, 4 waves.
// BIAS: 0 none, 1 col bias[col], 2 row bias[row]
// OUTM: 0 fp32, 1 bf16, 2 both (fp32 Ob + bf16 O2b), 3 fp32 tanh(acc/3)
// RS:   1 -> v = rowScale[z*sRS + row] * acc (+bias)
// BZDIV: B batch index = z / BZDIV
// Requirements: M % 128 == 0, K % 32 == 0, BT padded to gridDim.x*128 rows.
template<int BIAS, int OUTM, int RS, int BZDIV>
__global__ __launch_bounds__(256)
void gemm_mfma(const unsigned short* __restrict__ Ab, i64 sA,
               const unsigned short* __restrict__ Bb, i64 sB,
               const float* __restrict__ bias,
               void* __restrict__ Ob, i64 sO,
               unsigned short* __restrict__ O2b, i64 sO2,
               int Nn, int Kd, int ldA, int ldB, int ldO,
               const float* __restrict__ rowScale, i64 sRS)
{
  __shared__ unsigned short As[4096];   // 128 x 32 bf16 (8KB)
  __shared__ unsigned short Bs[4096];
  const int tid = threadIdx.x;
  const int w = tid >> 6, lane = tid & 63;
  const int z = blockIdx.z;
  const int m0 = blockIdx.y * 128, n0 = blockIdx.x * 128;
  const unsigned short* A = Ab + (i64)z * sA;
  const unsigned short* B = Bb + (i64)(BZDIV == 1 ? z : z / BZDIV) * sB;
  const int wr = w >> 1, wc = w & 1;
  const int r0 = tid >> 2, s0 = tid & 3;
  const int cL = lane & 15, sl = lane >> 4;

  f32x4 acc[4][4];
  #pragma unroll
  for (int i = 0; i < 4; ++i)
    #pragma unroll
    for (int j = 0; j < 4; ++j) acc[i][j] = (f32x4){0.f, 0.f, 0.f, 0.f};

  for (int k0 = 0; k0 < Kd; k0 += 32) {
    #pragma unroll
    for (int q = 0; q < 2; ++q) {
      int r = r0 + q * 64;
      int sg = s0 ^ ((r >> 1) & 3);
      const unsigned short* sa = A + (i64)(m0 + r) * ldA + k0 + sg * 8;
      const unsigned short* sb = B + (i64)(n0 + r) * ldB + k0 + sg * 8;
      __builtin_amdgcn_global_load_lds(
          (__attribute__((address_space(1))) void*)sa,
          (__attribute__((address_space(3))) void*)&As[(q * 256 + w * 64) * 8], 16, 0, 0);
      __builtin_amdgcn_global_load_lds(
          (__attribute__((address_space(1))) void*)sb,
          (__attribute__((address_space(3))) void*)&Bs[(q * 256 + w * 64) * 8], 16, 0, 0);
    }
    __syncthreads();
    bf16x8 af[4], bfv[4];
    #pragma unroll
    for (int mi = 0; mi < 4; ++mi) {
      int rr = wr * 64 + mi * 16 + cL;
      int se = sl ^ ((rr >> 1) & 3);
      af[mi] = *(const bf16x8*)&As[rr * 32 + se * 8];
    }
    #pragma unroll
    for (int ni = 0; ni < 4; ++ni) {
      int rr = wc * 64 + ni * 16 + cL;
      int se = sl ^ ((rr >> 1) & 3);
      bfv[ni] = *(const bf16x8*)&Bs[rr * 32 + se * 8];
    }
    #pragma unroll
    for (int mi = 0; mi < 4; ++mi)
      #pragma unroll
      for (int ni = 0; ni < 4; ++ni)
        acc[mi][ni] = __builtin_amdgcn_mfma_f32_16x16x32_bf16(af[mi], bfv[ni], acc[mi][ni], 0, 0, 0);
    __syncthreads();
  }

  // D layout: col=lane&15, row=(lane>>4)*4+reg
  #pragma unroll
  for (int mi = 0; mi < 4; ++mi) {
    const int rowb = m0 + wr * 64 + mi * 16 + sl * 4;
    #pragma unroll
    for (int ni = 0; ni < 4; ++ni) {
      const int col = n0 + wc * 64 + ni * 16 + cL;
      if (col < Nn) {
        float bc = (BIAS == 1) ? bias[col] : 0.f;
        #pragma unroll
        for (int rg = 0; rg < 4; ++rg) {
          float v = acc[mi][ni][rg];
          if (RS) v *= rowScale[(i64)z * sRS + rowb + rg];
          v += bc;
          if (BIAS == 2) v += bias[rowb + rg];
          i64 oidx = (i64)(rowb + rg) * ldO + col;
          if (OUTM == 0)      ((float*)Ob)[(i64)z * sO + oidx] = v;
          else if (OUTM == 1) ((unsigned short*)Ob)[(i64)z * sO + oidx] = f2b(v);
          else if (OUTM == 3) ((float*)Ob)[(i64)z * sO + oidx] = tanhf(v * (1.f / 3.f));
          else {
            ((float*)Ob)[(i64)z * sO + oidx] = v;
            O2b[(i64)z * sO2 + oidx] = f2b(v);
          }
        }
      }
    }
  }
}

// ================= fused emo pass =================
// one read of emo -> colPart (col-sum partials), dotE = emo_row . eleW[0:1024], emoB = bf16(emo)
__global__ __launch_bounds__(256)
void emo_pass1(const float* __restrict__ emo, const float* __restrict__ eleW,
               unsigned short* __restrict__ emoB, float* __restrict__ colPart,
               float* __restrict__ dotE) {
  int b = blockIdx.y, lc = blockIdx.x;   // 16 chunks x 64 rows
  int t = threadIdx.x, lane = t & 63, w = t >> 6;
  float4 w4 = ((const float4*)eleW)[t];
  float4 acc = make_float4(0.f, 0.f, 0.f, 0.f);
  __shared__ float dw[64][4];
  const float4* src = (const float4*)emo + ((i64)b * 1024 + lc * 64) * 256;
  ushort4* dst = (ushort4*)emoB + ((i64)b * 1024 + lc * 64) * 256;
  for (int lr = 0; lr < 64; ++lr) {
    float4 v = src[lr * 256 + t];
    acc.x += v.x; acc.y += v.y; acc.z += v.z; acc.w += v.w;
    float d = v.x * w4.x + v.y * w4.y + v.z * w4.z + v.w * w4.w;
    #pragma unroll
    for (int o = 32; o; o >>= 1) d += __shfl_xor(d, o);
    if (!lane) dw[lr][w] = d;
    ushort4 o4; o4.x = f2b(v.x); o4.y = f2b(v.y); o4.z = f2b(v.z); o4.w = f2b(v.w);
    dst[lr * 256 + t] = o4;
  }
  __syncthreads();
  if (t < 64) dotE[(i64)b * 1024 + lc * 64 + t] = dw[t][0] + dw[t][1] + dw[t][2] + dw[t][3];
  ((float4*)colPart)[((i64)b * 16 + lc) * 256 + t] = acc;
}

__global__ void colmean2(const float* __restrict__ colPart, float* __restrict__ emomean) {
  int b = blockIdx.y, e = blockIdx.x * 256 + threadIdx.x;
  float s = 0.f;
  #pragma unroll
  for (int lc = 0; lc < 16; ++lc) s += colPart[((i64)b * 16 + lc) * 1024 + e];
  emomean[b * 1024 + e] = s * (1.f / 1024.f);
}

// ================= prep kernels =================
__global__ __launch_bounds__(256)
void transpose_w(const float* __restrict__ in, unsigned short* __restrict__ out,
                 int Kd, int N, int Npad) {
  __shared__ float T[32][33];
  int n0 = blockIdx.x * 32, k0 = blockIdx.y * 32;
  int t = threadIdx.x;
  #pragma unroll
  for (int p = 0; p < 4; ++p) {
    int idx = t + 256 * p; int kk = idx >> 5, nn = idx & 31;
    float v = 0.f;
    if (n0 + nn < N && k0 + kk < Kd) v = in[(i64)(k0 + kk) * N + (n0 + nn)];
    T[nn][kk] = v;
  }
  __syncthreads();
  #pragma unroll
  for (int p = 0; p < 4; ++p) {
    int idx = t + 256 * p; int nn = idx >> 5, kk = idx & 31;
    if (n0 + nn < Npad && k0 + kk < Kd) out[(i64)(n0 + nn) * Kd + (k0 + kk)] = f2b(T[nn][kk]);
  }
}

__global__ void kvr_bias_kernel(const float* wkb, const float* wvb, const float* wrb, float* out) {
  int t = blockIdx.x * 256 + threadIdx.x;
  if (t >= 480) return;
  out[t] = (t < 448) ? wkb[t] : (t < 476) ? wvb[t - 448] : (t < 479) ? wrb[t - 476] : 0.f;
}

__global__ void pool_phr(const float* __restrict__ phr, unsigned short* __restrict__ out) {
  i64 idx = (i64)blockIdx.x * 256 + threadIdx.x;
  if (idx >= 2097152) return;
  i64 bm = idx >> 8; int c = (int)(idx & 255);
  i64 b = bm >> 8, m = bm & 255;
  const float4* r0 = (const float4*)(phr + (b * 512 + 2 * m) * 1024) + c;
  const float4* r1 = (const float4*)(phr + (b * 512 + 2 * m + 1) * 1024) + c;
  float4 a = *r0, d = *r1;
  ushort4 o;
  o.x = f2b(0.5f * (a.x + d.x)); o.y = f2b(0.5f * (a.y + d.y));
  o.z = f2b(0.5f * (a.z + d.z)); o.w = f2b(0.5f * (a.w + d.w));
  ((ushort4*)out)[idx] = o;
}

__global__ void vconv(const float* __restrict__ video, unsigned short* __restrict__ combine) {
  i64 idx = (i64)blockIdx.x * 256 + threadIdx.x;
  if (idx >= 2097152) return;
  i64 b = idx >> 16, r = idx & 65535;
  float4 v = ((const float4*)video)[idx];
  ushort4 o;
  o.x = f2b(v.x); o.y = f2b(v.y); o.z = f2b(v.z); o.w = f2b(v.w);
  ((ushort4*)combine)[b * 131072 + 65536 + r] = o;
}

// VT[b][n][k] = KVR[b][k][448+n] (n<28), 0 pad to 128 rows
__global__ void vt_fill(const unsigned short* __restrict__ KVR, unsigned short* __restrict__ VT) {
  int b = blockIdx.y;
  int idx = blockIdx.x * 256 + threadIdx.x;   // 64 blocks x 256 = 16384
  int n = idx >> 7, k = idx & 127;
  unsigned short v = 0;
  if (n < 28) v = KVR[(i64)b * 61440 + k * 480 + 448 + n];
  VT[((i64)b * 128 + n) * 128 + k] = v;
}

// ================= softmax / routing =================
__global__ void softmax_attn_a(const float* __restrict__ logits, unsigned short* __restrict__ outT) {
  int gw = (int)(((i64)blockIdx.x * blockDim.x + threadIdx.x) >> 6);
  int lane = threadIdx.x & 63;
  if (gw >= 32 * 512) return;
  int b = gw >> 9, m = gw & 511;
  const float* p = logits + (i64)gw * 128;
  float x0 = p[lane], x1 = p[lane + 64];
  float mx = fmaxf(x0, x1);
  #pragma unroll
  for (int o = 32; o; o >>= 1) mx = fmaxf(mx, __shfl_xor(mx, o));
  float e0 = expf(x0 - mx), e1 = expf(x1 - mx);
  float s = e0 + e1;
  #pragma unroll
  for (int o = 32; o; o >>= 1) s += __shfl_xor(s, o);
  float inv = 1.f / s;
  unsigned short* o0 = outT + (i64)b * 128 * 512 + m;
  o0[(i64)lane * 512] = f2b(e0 * inv);
  o0[(i64)(lane + 64) * 512] = f2b(e1 * inv);
}

__global__ void softmax_P_bf(const unsigned short* __restrict__ PL, unsigned short* __restrict__ P) {
  i64 gw = ((i64)blockIdx.x * blockDim.x + threadIdx.x) >> 6;
  int lane = threadIdx.x & 63;
  if (gw >= 98304) return;
  const unsigned short* p = PL + gw * 128;
  float x0 = b2f(p[lane]) * TEMP_ISQ, x1 = b2f(p[lane + 64]) * TEMP_ISQ;
  float mx = fmaxf(x0, x1);
  #pragma unroll
  for (int o = 32; o; o >>= 1) mx = fmaxf(mx, __shfl_xor(mx, o));
  float e0 = expf(x0 - mx), e1 = expf(x1 - mx);
  float s = e0 + e1;
  #pragma unroll
  for (int o = 32; o; o >>= 1) s += __shfl_xor(s, o);
  float inv = 1.f / s;
  P[gw * 128 + lane] = f2b(e0 * inv);
  P[gw * 128 + lane + 64] = f2b(e1 * inv);
}

__global__ void apool_kernel(const float* __restrict__ emomean, const float* __restrict__ agg,
                             float* __restrict__ Apool) {
  int gw = (int)(((i64)blockIdx.x * blockDim.x + threadIdx.x) >> 6);
  int lane = threadIdx.x & 63;
  if (gw >= 32 * 128) return;
  int b = gw >> 7, k = gw & 127;
  const float* ag = agg + ((i64)b * 128 + k) * 1024;
  const float* em = emomean + (i64)b * 1024;
  float s = 0.f;
  #pragma unroll
  for (int j = 0; j < 16; ++j) { int e = j * 64 + lane; s += em[e] * ag[e]; }
  #pragma unroll
  for (int o = 32; o; o >>= 1) s += __shfl_down(s, o);
  if (!lane) Apool[gw] = s;
}

// route stage 1: partial over k-range of 32
__global__ void route1_kernel(const float* __restrict__ Apool, const float* __restrict__ agg,
                              float* __restrict__ routePart) {
  int b = blockIdx.z, kc = blockIdx.y;
  int e = blockIdx.x * 256 + threadIdx.x;
  __shared__ float Ap[32];
  if (threadIdx.x < 32) Ap[threadIdx.x] = Apool[b * 128 + kc * 32 + threadIdx.x];
  __syncthreads();
  const float* ag = agg + ((i64)b * 128 + kc * 32) * 1024 + e;
  float s = 0.f;
  #pragma unroll
  for (int k = 0; k < 32; ++k) s += Ap[k] * ag[(i64)k * 1024];
  routePart[((i64)kc * 32 + b) * 1024 + e] = s;
}
__global__ void route2_kernel(const float* __restrict__ routePart, float* __restrict__ route) {
  int b = blockIdx.y, e = blockIdx.x * 256 + threadIdx.x;
  float s = 0.f;
  #pragma unroll
  for (int kc = 0; kc < 4; ++kc) s += routePart[((i64)kc * 32 + b) * 1024 + e];
  route[b * 1024 + e] = s;
}

__global__ void rb_kernel(const float* __restrict__ route, const float* __restrict__ eleW,
                          const float* __restrict__ eleb, float* __restrict__ rb) {
  int b = blockIdx.x, t = threadIdx.x;
  float s = 0.f;
  for (int j = t; j < 1024; j += 256) s += route[b * 1024 + j] * eleW[1024 + j];
  __shared__ float red[256];
  red[t] = s; __syncthreads();
  for (int o = 128; o > 0; o >>= 1) { if (t < o) red[t] += red[t + o]; __syncthreads(); }
  if (t == 0) rb[b] = red[0] + eleb[0];
}

__global__ void re_small(const float* __restrict__ dotE, const float* __restrict__ rb,
                         float* __restrict__ Re) {
  int i = blockIdx.x * 256 + threadIdx.x;   // 32768
  Re[i] = tanhf(dotE[i] + rb[i >> 10]);
}

// ================= P consumers =================
__global__ void pmean1_kernel(const unsigned short* __restrict__ P, float* __restrict__ Ppart) {
  int bi = blockIdx.x, c = blockIdx.y, k = threadIdx.x;
  const unsigned short* p = P + ((i64)bi * 1024 + c * 128) * 128 + k;
  float s = 0.f;
  for (int l = 0; l < 128; ++l) s += b2f(p[(i64)l * 128]);
  Ppart[((i64)bi * 8 + c) * 128 + k] = s;
}
__global__ void pmean2_kernel(const float* __restrict__ Ppart, float* __restrict__ Pmean) {
  int bi = blockIdx.x, k = threadIdx.x;
  float s = 0.f;
  #pragma unroll
  for (int c = 0; c < 8; ++c) s += Ppart[((i64)bi * 8 + c) * 128 + k];
  Pmean[bi * 128 + k] = s * (1.f / 1024.f);
}

__global__ void rdiag_gate_kernel(const float* __restrict__ Pmean, const unsigned short* __restrict__ KVR,
                                  float* __restrict__ gate) {
  int b = blockIdx.x, t = threadIdx.x;  // 128 threads
  __shared__ float red[128];
  __shared__ float rd[3];
  for (int i = 0; i < 3; ++i) {
    float v = Pmean[((i64)b * 3 + i) * 128 + t] * b2f(KVR[(i64)b * 61440 + t * 480 + 476 + i]);
    red[t] = v; __syncthreads();
    for (int o = 64; o > 0; o >>= 1) { if (t < o) red[t] += red[t + o]; __syncthreads(); }
    if (t == 0) rd[i] = red[0];
    __syncthreads();
  }
  if (t == 0) {
    float m = fmaxf(rd[0], fmaxf(rd[1], rd[2]));
    float e0 = expf(rd[0] - m), e1 = expf(rd[1] - m), e2 = expf(rd[2] - m);
    float inv = 1.f / (e0 + e1 + e2);
    gate[b * 3 + 0] = e0 * inv; gate[b * 3 + 1] = e1 * inv; gate[b * 3 + 2] = e2 * inv;
  }
}

__global__ __launch_bounds__(256)
void final_kernel(const float* __restrict__ emo, const float* __restrict__ Re,
                  const float* __restrict__ O, const float* __restrict__ gate,
                  float* __restrict__ out) {
  i64 bl = blockIdx.x;
  int b = (int)(bl >> 10), l = (int)(bl & 1023);
  __shared__ float Gg[16];
  int t = threadIdx.x;
  if (t < 16) {
    float g0 = gate[b * 3], g1 = gate[b * 3 + 1], g2 = gate[b * 3 + 2];
    float o0 = O[((i64)(b * 3 + 0) * 1024 + l) * 28 + (t >> 2)];
    float o1 = O[((i64)(b * 3 + 1) * 1024 + l) * 28 + 4 + (t >> 1)];
    float o2 = O[((i64)(b * 3 + 2) * 1024 + l) * 28 + 12 + t];
    Gg[t] = g0 * o0 + g1 * o1 + g2 * o2;
  }
  __syncthreads();
  float re = Re[bl];
  float4 e4 = ((const float4*)(emo + bl * 1024))[t];
  float g = 1.f + re * Gg[t >> 4];
  ((float4*)(out + bl * 1024))[t] = make_float4(e4.x * g, e4.y * g, e4.z * g, e4.w * g);
}

// ================= launcher =================
extern "C" void kernel_launch(void* const* d_in, const int* in_sizes, int n_in,
                              void* d_out, int out_size, void* d_ws, size_t ws_size,
                              hipStream_t stream) {
  const float* emo     = (const float*)d_in[0];
  const float* phr     = (const float*)d_in[1];
  const float* video   = (const float*)d_in[2];
  const float* w_v_W   = (const float*)d_in[3];
  const float* w_v_b   = (const float*)d_in[4];
  const float* agg_a_W = (const float*)d_in[5];
  const float* agg_a_b = (const float*)d_in[6];
  const float* agg_c_W = (const float*)d_in[7];
  const float* agg_c_b = (const float*)d_in[8];
  const float* ele_W   = (const float*)d_in[9];
  const float* ele_b   = (const float*)d_in[10];
  const float* wq_W    = (const float*)d_in[11];
  const float* wq_b    = (const float*)d_in[12];
  const float* wk_W    = (const float*)d_in[13];
  const float* wk_b    = (const float*)d_in[14];
  const float* wv_W    = (const float*)d_in[15];
  const float* wv_b    = (const float*)d_in[16];
  const float* wr_W    = (const float*)d_in[17];
  const float* wr_b    = (const float*)d_in[18];

  char* ws = (char*)d_ws;
  // ---- region map (bytes) ----
  const i64 oEmoB    = 0;            // ushort [32,1024,1024] 67,108,864 (dead after G6)
  const i64 oP       = 0;            //   overlay: ushort [96,1024,128] 25,165,824
  const i64 oO       = 25165824;     //   overlay: float  [96,1024,28]  11,010,048
  const i64 oCombine = 67108864;     // ushort [32,512,1024] 33,554,432 (dead after G3')
  const i64 oPL      = 67108864;     //   overlay: ushort [32,3,1024,128] 25,165,824
  const i64 oPooled  = 100663296;    // ushort [32,256,1024] 16,777,216 (dead after G1)
  const i64 oLogitsA = 100663296;    //   overlay: float [32,512,128] 8,388,608 (dead after softmax_attn_a)
  const i64 oAggF    = 100663296;    //   overlay: float [32,128,1024] 16,777,216
  const i64 oCT      = 117440512;    // ushort [32,1024,512] 33,554,432 (dead after G4)
  const i64 oQ       = 117440512;    //   overlay: ushort [32,1024,448] 29,360,128
  const i64 oAttnAT  = 150994944;    // ushort [32,128,512] 4,194,304
  const i64 oAggB    = 155189248;    // ushort [32,128,1024] 8,388,608
  const i64 oWvT     = 163577856;    // 2,097,152
  const i64 oAaT     = 165675008;    // 262,144
  const i64 oAcT     = 165937152;    // 2,097,152
  const i64 oWqT     = 168034304;    // 1,048,576
  const i64 oKvrT    = 169082880;    // 1,048,576
  const i64 oKVR     = 170131456;    // ushort [32,128,480] 3,932,160
  const i64 oVT      = 174063616;    // ushort [32,128,128] 1,048,576
  const i64 oKvrB    = 175112192;    // 4,096
  const i64 oEmomean = 175116288;    // 131,072
  const i64 oColPart = 175247360;    // float [32,16,1024] 2,097,152
  const i64 oDotE    = 177344512;    // 131,072
  const i64 oApool   = 177475584;    // 16,384
  const i64 oRoutePt = 177491968;    // float [4,32,1024] 524,288
  const i64 oRoute   = 178016256;    // 131,072
  const i64 oRb      = 178147328;    // 256
  const i64 oRe      = 178147584;    // 131,072
  const i64 oPpart   = 178278656;    // 393,216
  const i64 oPmean   = 178671872;    // 49,152
  const i64 oGate    = 178721024;    // 512

  unsigned short* emoB    = (unsigned short*)(ws + oEmoB);
  unsigned short* P       = (unsigned short*)(ws + oP);
  float*          O       = (float*)(ws + oO);
  unsigned short* combine = (unsigned short*)(ws + oCombine);
  unsigned short* PL      = (unsigned short*)(ws + oPL);
  unsigned short* pooled  = (unsigned short*)(ws + oPooled);
  float*          logitsA = (float*)(ws + oLogitsA);
  float*          aggF    = (float*)(ws + oAggF);
  unsigned short* CT      = (unsigned short*)(ws + oCT);
  unsigned short* Q       = (unsigned short*)(ws + oQ);
  unsigned short* attnAT  = (unsigned short*)(ws + oAttnAT);
  unsigned short* aggB    = (unsigned short*)(ws + oAggB);
  unsigned short* wvT     = (unsigned short*)(ws + oWvT);
  unsigned short* aaT     = (unsigned short*)(ws + oAaT);
  unsigned short* acT     = (unsigned short*)(ws + oAcT);
  unsigned short* wqT     = (unsigned short*)(ws + oWqT);
  unsigned short* kvrT    = (unsigned short*)(ws + oKvrT);
  unsigned short* KVR     = (unsigned short*)(ws + oKVR);
  unsigned short* VT      = (unsigned short*)(ws + oVT);
  float*          kvrB    = (float*)(ws + oKvrB);
  float*          emomean = (float*)(ws + oEmomean);
  float*          colPart = (float*)(ws + oColPart);
  float*          dotE    = (float*)(ws + oDotE);
  float*          Apool   = (float*)(ws + oApool);
  float*          routePt = (float*)(ws + oRoutePt);
  float*          route   = (float*)(ws + oRoute);
  float*          rbv     = (float*)(ws + oRb);
  float*          Re      = (float*)(ws + oRe);
  float*          Ppart   = (float*)(ws + oPpart);
  float*          Pmean   = (float*)(ws + oPmean);
  float*          gate    = (float*)(ws + oGate);

  dim3 blk(256);

  // fused emo pass: colPart + dotE + emoB
  emo_pass1<<<dim3(16, 32), blk, 0, stream>>>(emo, ele_W, emoB, colPart, dotE);

  // weight prep
  transpose_w<<<dim3(32, 32), blk, 0, stream>>>(w_v_W, wvT, 1024, 1024, 1024);
  transpose_w<<<dim3(4, 32),  blk, 0, stream>>>(agg_a_W, aaT, 1024, 128, 128);
  transpose_w<<<dim3(32, 32), blk, 0, stream>>>(agg_c_W, acT, 1024, 1024, 1024);
  transpose_w<<<dim3(16, 32), blk, 0, stream>>>(wq_W, wqT, 1024, 448, 512);
  transpose_w<<<dim3(14, 32), blk, 0, stream>>>(wk_W, kvrT, 1024, 448, 448);
  transpose_w<<<dim3(1, 32),  blk, 0, stream>>>(wv_W, kvrT + (i64)448 * 1024, 1024, 28, 28);
  transpose_w<<<dim3(2, 32),  blk, 0, stream>>>(wr_W, kvrT + (i64)476 * 1024, 1024, 3, 36);
  kvr_bias_kernel<<<2, blk, 0, stream>>>(wk_b, wv_b, wr_b, kvrB);

  // feature aggregation
  pool_phr<<<8192, blk, 0, stream>>>(phr, pooled);
  vconv<<<8192, blk, 0, stream>>>(video, combine);
  // G1: combine[0:256] = pooled @ w_v + b
  gemm_mfma<1, 1, 0, 1><<<dim3(8, 2, 32), blk, 0, stream>>>(pooled, 262144, wvT, 0, w_v_b,
      (void*)combine, 524288, nullptr, 0, 1024, 1024, 1024, 1024, 1024, nullptr, 0);
  // G2: logitsA = combine @ agg_a + b
  gemm_mfma<1, 0, 0, 1><<<dim3(1, 4, 32), blk, 0, stream>>>(combine, 524288, aaT, 0, agg_a_b,
      (void*)logitsA, 65536, nullptr, 0, 128, 1024, 1024, 1024, 128, nullptr, 0);
  softmax_attn_a<<<4096, blk, 0, stream>>>(logitsA, attnAT);
  // G3': CT = agg_cT @ combine^T + agg_c_b (row bias)
  gemm_mfma<2, 1, 0, 1><<<dim3(4, 8, 32), blk, 0, stream>>>(acT, 0, combine, 524288, agg_c_b,
      (void*)CT, 524288, nullptr, 0, 512, 1024, 1024, 1024, 512, nullptr, 0);
  // G4: agg = attnAT @ CT^T (fp32 + bf16)
  gemm_mfma<0, 2, 0, 1><<<dim3(8, 1, 32), blk, 0, stream>>>(attnAT, 65536, CT, 524288, nullptr,
      (void*)aggF, 131072, aggB, 131072, 1024, 512, 512, 512, 1024, nullptr, 0);

  // element routing (fp32)
  colmean2<<<dim3(4, 32), blk, 0, stream>>>(colPart, emomean);
  apool_kernel<<<1024, blk, 0, stream>>>(emomean, aggF, Apool);
  route1_kernel<<<dim3(4, 4, 32), blk, 0, stream>>>(Apool, aggF, routePt);
  route2_kernel<<<dim3(4, 32), blk, 0, stream>>>(routePt, route);
  rb_kernel<<<32, blk, 0, stream>>>(route, ele_W, ele_b, rbv);
  re_small<<<128, blk, 0, stream>>>(dotE, rbv, Re);

  // KVR = agg @ [wk|wv|wr] + bias
  gemm_mfma<1, 1, 0, 1><<<dim3(4, 1, 32), blk, 0, stream>>>(aggB, 131072, kvrT, 0, kvrB,
      (void*)KVR, 61440, nullptr, 0, 480, 1024, 1024, 1024, 480, nullptr, 0);
  vt_fill<<<dim3(64, 32), blk, 0, stream>>>(KVR, VT);
  // G6: Q = Re * (emoB @ wq) + b  (row-scale epilogue)
  gemm_mfma<1, 1, 1, 1><<<dim3(4, 8, 32), blk, 0, stream>>>(emoB, 1048576, wqT, 0, wq_b,
      (void*)Q, 458752, nullptr, 0, 448, 1024, 1024, 1024, 448, Re, 1024);

  // G8: PL[i] = Q_blk @ K_blk^T (bf16 logits)
  const int doffs[3] = {0, 256, 384};
  const int kds[3]   = {256, 128, 64};
  for (int i = 0; i < 3; ++i) {
    gemm_mfma<0, 1, 0, 1><<<dim3(1, 8, 32), blk, 0, stream>>>(Q + doffs[i], 458752,
        KVR + doffs[i], 61440, nullptr,
        (void*)(PL + (i64)i * 131072), 393216, nullptr, 0, 128, kds[i], 448, 480, 128, nullptr, 0);
  }
  softmax_P_bf<<<24576, blk, 0, stream>>>(PL, P);
  pmean1_kernel<<<dim3(96, 8), 128, 0, stream>>>(P, Ppart);
  pmean2_kernel<<<96, 128, 0, stream>>>(Ppart, Pmean);
  // OV: O = tanh((P @ VT^T)/3), fp32 out
  gemm_mfma<0, 3, 0, 3><<<dim3(1, 8, 96), blk, 0, stream>>>(P, 131072, VT, 16384, nullptr,
      (void*)O, 28672, nullptr, 0, 28, 128, 128, 128, 28, nullptr, 0);
  rdiag_gate_kernel<<<32, 128, 0, stream>>>(Pmean, KVR, gate);
  final_kernel<<<32768, blk, 0, stream>>>(emo, Re, O, gate, (float*)d_out);
}

// Round 4
// 472.592 us; speedup vs baseline: 4.9665x; 1.1040x over previous
//
#include <hip/hip_runtime.h>
#include <math.h>

typedef long long i64;
typedef __attribute__((ext_vector_type(8))) short bf16x8;
typedef __attribute__((ext_vector_type(4))) float f32x4;

#define TEMP_ISQ 0.047245559f   // 1/sqrt(448)

__device__ __forceinline__ unsigned short f2b(float x) {
  union { float f; unsigned u; } a; a.f = x;
  return (unsigned short)((a.u + 0x7fffu + ((a.u >> 16) & 1u)) >> 16);
}
__device__ __forceinline__ float b2f(unsigned short b) {
  union { float f; unsigned u; } a; a.u = ((unsigned)b) << 16; return a.f;
}

// ================= NT bf16 MFMA GEMM =================
// out[M,N] = A[M,K] @ BT[N,K]^T (+bias). 128x128 tile, BK=64, 4 waves.
// T1 chunked XCD swizzle on flattened block id (requires nwg % 8 == 0).
// BIAS: 0 none, 1 col bias[col], 2 row bias[row]
// OUTM: 0 fp32, 1 bf16, 2 both (fp32 Ob + bf16 O2b), 3 fp32 tanh(acc/3)
// RS:   1 -> v = rowScale[z*sRS + row] * acc (+bias)
// BZDIV: B batch index = z / BZDIV
// Requirements: M % 128 == 0, K % 64 == 0, BT padded to gridDim.x*128 rows.
template<int BIAS, int OUTM, int RS, int BZDIV>
__global__ __launch_bounds__(256)
void gemm_mfma(const unsigned short* __restrict__ Ab, i64 sA,
               const unsigned short* __restrict__ Bb, i64 sB,
               const float* __restrict__ bias,
               void* __restrict__ Ob, i64 sO,
               unsigned short* __restrict__ O2b, i64 sO2,
               int Nn, int Kd, int ldA, int ldB, int ldO,
               const float* __restrict__ rowScale, i64 sRS)
{
  __shared__ unsigned short As[8192];   // 128 x 64 bf16 (16KB)
  __shared__ unsigned short Bs[8192];
  const int tid = threadIdx.x;
  const int w = tid >> 6, lane = tid & 63;

  // T1 chunked XCD swizzle
  const int gx = gridDim.x, gy = gridDim.y;
  int nwg = gx * gy * gridDim.z;
  int bid = blockIdx.x + gx * (blockIdx.y + gy * blockIdx.z);
  int L = bid;
  if ((nwg & 7) == 0) L = (bid & 7) * (nwg >> 3) + (bid >> 3);
  const int bx = L % gx;
  int rem = L / gx;
  const int by = rem % gy;
  const int z  = rem / gy;

  const int m0 = by * 128, n0 = bx * 128;
  const unsigned short* A = Ab + (i64)z * sA;
  const unsigned short* B = Bb + (i64)(BZDIV == 1 ? z : z / BZDIV) * sB;
  const int wr = w >> 1, wc = w & 1;
  const int rS = tid >> 3, sS = tid & 7;       // stage: row, slot
  const int cL = lane & 15, sl = lane >> 4;

  f32x4 acc[4][4];
  #pragma unroll
  for (int i = 0; i < 4; ++i)
    #pragma unroll
    for (int j = 0; j < 4; ++j) acc[i][j] = (f32x4){0.f, 0.f, 0.f, 0.f};

  for (int k0 = 0; k0 < Kd; k0 += 64) {
    // stage 128x64 tiles; LDS linear dest, source slot pre-XOR'd (rule #21)
    #pragma unroll
    for (int q = 0; q < 4; ++q) {
      int r = rS + q * 32;
      int sg = sS ^ (r & 7);
      const unsigned short* sa = A + (i64)(m0 + r) * ldA + k0 + sg * 8;
      const unsigned short* sb = B + (i64)(n0 + r) * ldB + k0 + sg * 8;
      __builtin_amdgcn_global_load_lds(
          (__attribute__((address_space(1))) void*)sa,
          (__attribute__((address_space(3))) void*)&As[r * 64 + sS * 8], 16, 0, 0);
      __builtin_amdgcn_global_load_lds(
          (__attribute__((address_space(1))) void*)sb,
          (__attribute__((address_space(3))) void*)&Bs[r * 64 + sS * 8], 16, 0, 0);
    }
    __syncthreads();
    bf16x8 af[2][4], bfv[2][4];
    #pragma unroll
    for (int kk = 0; kk < 2; ++kk) {
      #pragma unroll
      for (int mi = 0; mi < 4; ++mi) {
        int rr = wr * 64 + mi * 16 + cL;
        int ph = (kk * 4 + sl) ^ (rr & 7);
        af[kk][mi] = *(const bf16x8*)&As[rr * 64 + ph * 8];
      }
      #pragma unroll
      for (int ni = 0; ni < 4; ++ni) {
        int rr = wc * 64 + ni * 16 + cL;
        int ph = (kk * 4 + sl) ^ (rr & 7);
        bfv[kk][ni] = *(const bf16x8*)&Bs[rr * 64 + ph * 8];
      }
    }
    #pragma unroll
    for (int kk = 0; kk < 2; ++kk)
      #pragma unroll
      for (int mi = 0; mi < 4; ++mi)
        #pragma unroll
        for (int ni = 0; ni < 4; ++ni)
          acc[mi][ni] = __builtin_amdgcn_mfma_f32_16x16x32_bf16(af[kk][mi], bfv[kk][ni], acc[mi][ni], 0, 0, 0);
    __syncthreads();
  }

  // D layout: col=lane&15, row=(lane>>4)*4+reg
  #pragma unroll
  for (int mi = 0; mi < 4; ++mi) {
    const int rowb = m0 + wr * 64 + mi * 16 + sl * 4;
    #pragma unroll
    for (int ni = 0; ni < 4; ++ni) {
      const int col = n0 + wc * 64 + ni * 16 + cL;
      if (col < Nn) {
        float bc = (BIAS == 1) ? bias[col] : 0.f;
        #pragma unroll
        for (int rg = 0; rg < 4; ++rg) {
          float v = acc[mi][ni][rg];
          if (RS) v *= rowScale[(i64)z * sRS + rowb + rg];
          v += bc;
          if (BIAS == 2) v += bias[rowb + rg];
          i64 oidx = (i64)(rowb + rg) * ldO + col;
          if (OUTM == 0)      ((float*)Ob)[(i64)z * sO + oidx] = v;
          else if (OUTM == 1) ((unsigned short*)Ob)[(i64)z * sO + oidx] = f2b(v);
          else if (OUTM == 3) ((float*)Ob)[(i64)z * sO + oidx] = tanhf(v * (1.f / 3.f));
          else {
            ((float*)Ob)[(i64)z * sO + oidx] = v;
            O2b[(i64)z * sO2 + oidx] = f2b(v);
          }
        }
      }
    }
  }
}

// ================= fused emo pass =================
__global__ __launch_bounds__(256)
void emo_pass1(const float* __restrict__ emo, const float* __restrict__ eleW,
               unsigned short* __restrict__ emoB, float* __restrict__ colPart,
               float* __restrict__ dotE) {
  int b = blockIdx.y, lc = blockIdx.x;   // 16 chunks x 64 rows
  int t = threadIdx.x, lane = t & 63, w = t >> 6;
  float4 w4 = ((const float4*)eleW)[t];
  float4 acc = make_float4(0.f, 0.f, 0.f, 0.f);
  __shared__ float dw[64][4];
  const float4* src = (const float4*)emo + ((i64)b * 1024 + lc * 64) * 256;
  ushort4* dst = (ushort4*)emoB + ((i64)b * 1024 + lc * 64) * 256;
  for (int lr = 0; lr < 64; ++lr) {
    float4 v = src[lr * 256 + t];
    acc.x += v.x; acc.y += v.y; acc.z += v.z; acc.w += v.w;
    float d = v.x * w4.x + v.y * w4.y + v.z * w4.z + v.w * w4.w;
    #pragma unroll
    for (int o = 32; o; o >>= 1) d += __shfl_xor(d, o);
    if (!lane) dw[lr][w] = d;
    ushort4 o4; o4.x = f2b(v.x); o4.y = f2b(v.y); o4.z = f2b(v.z); o4.w = f2b(v.w);
    dst[lr * 256 + t] = o4;
  }
  __syncthreads();
  if (t < 64) dotE[(i64)b * 1024 + lc * 64 + t] = dw[t][0] + dw[t][1] + dw[t][2] + dw[t][3];
  ((float4*)colPart)[((i64)b * 16 + lc) * 256 + t] = acc;
}

__global__ void colmean2(const float* __restrict__ colPart, float* __restrict__ emomean) {
  int b = blockIdx.y, e = blockIdx.x * 256 + threadIdx.x;
  float s = 0.f;
  #pragma unroll
  for (int lc = 0; lc < 16; ++lc) s += colPart[((i64)b * 16 + lc) * 1024 + e];
  emomean[b * 1024 + e] = s * (1.f / 1024.f);
}

// ================= prep kernels =================
__global__ __launch_bounds__(256)
void transpose_w(const float* __restrict__ in, unsigned short* __restrict__ out,
                 int Kd, int N, int Npad) {
  __shared__ float T[32][33];
  int n0 = blockIdx.x * 32, k0 = blockIdx.y * 32;
  int t = threadIdx.x;
  #pragma unroll
  for (int p = 0; p < 4; ++p) {
    int idx = t + 256 * p; int kk = idx >> 5, nn = idx & 31;
    float v = 0.f;
    if (n0 + nn < N && k0 + kk < Kd) v = in[(i64)(k0 + kk) * N + (n0 + nn)];
    T[nn][kk] = v;
  }
  __syncthreads();
  #pragma unroll
  for (int p = 0; p < 4; ++p) {
    int idx = t + 256 * p; int nn = idx >> 5, kk = idx & 31;
    if (n0 + nn < Npad && k0 + kk < Kd) out[(i64)(n0 + nn) * Kd + (k0 + kk)] = f2b(T[nn][kk]);
  }
}

__global__ void kvr_bias_kernel(const float* wkb, const float* wvb, const float* wrb, float* out) {
  int t = blockIdx.x * 256 + threadIdx.x;
  if (t >= 480) return;
  out[t] = (t < 448) ? wkb[t] : (t < 476) ? wvb[t - 448] : (t < 479) ? wrb[t - 476] : 0.f;
}

__global__ void pool_phr(const float* __restrict__ phr, unsigned short* __restrict__ out) {
  i64 idx = (i64)blockIdx.x * 256 + threadIdx.x;
  if (idx >= 2097152) return;
  i64 bm = idx >> 8; int c = (int)(idx & 255);
  i64 b = bm >> 8, m = bm & 255;
  const float4* r0 = (const float4*)(phr + (b * 512 + 2 * m) * 1024) + c;
  const float4* r1 = (const float4*)(phr + (b * 512 + 2 * m + 1) * 1024) + c;
  float4 a = *r0, d = *r1;
  ushort4 o;
  o.x = f2b(0.5f * (a.x + d.x)); o.y = f2b(0.5f * (a.y + d.y));
  o.z = f2b(0.5f * (a.z + d.z)); o.w = f2b(0.5f * (a.w + d.w));
  ((ushort4*)out)[idx] = o;
}

__global__ void vconv(const float* __restrict__ video, unsigned short* __restrict__ combine) {
  i64 idx = (i64)blockIdx.x * 256 + threadIdx.x;
  if (idx >= 2097152) return;
  i64 b = idx >> 16, r = idx & 65535;
  float4 v = ((const float4*)video)[idx];
  ushort4 o;
  o.x = f2b(v.x); o.y = f2b(v.y); o.z = f2b(v.z); o.w = f2b(v.w);
  ((ushort4*)combine)[b * 131072 + 65536 + r] = o;
}

// VT[b][n][k] = KVR[b][k][448+n] (n<28), 0 pad to 128 rows
__global__ void vt_fill(const unsigned short* __restrict__ KVR, unsigned short* __restrict__ VT) {
  int b = blockIdx.y;
  int idx = blockIdx.x * 256 + threadIdx.x;
  int n = idx >> 7, k = idx & 127;
  unsigned short v = 0;
  if (n < 28) v = KVR[(i64)b * 61440 + k * 480 + 448 + n];
  VT[((i64)b * 128 + n) * 128 + k] = v;
}

// ================= softmax / routing =================
__global__ void softmax_attn_a(const float* __restrict__ logits, unsigned short* __restrict__ outT) {
  int gw = (int)(((i64)blockIdx.x * blockDim.x + threadIdx.x) >> 6);
  int lane = threadIdx.x & 63;
  if (gw >= 32 * 512) return;
  int b = gw >> 9, m = gw & 511;
  const float* p = logits + (i64)gw * 128;
  float x0 = p[lane], x1 = p[lane + 64];
  float mx = fmaxf(x0, x1);
  #pragma unroll
  for (int o = 32; o; o >>= 1) mx = fmaxf(mx, __shfl_xor(mx, o));
  float e0 = expf(x0 - mx), e1 = expf(x1 - mx);
  float s = e0 + e1;
  #pragma unroll
  for (int o = 32; o; o >>= 1) s += __shfl_xor(s, o);
  float inv = 1.f / s;
  unsigned short* o0 = outT + (i64)b * 128 * 512 + m;
  o0[(i64)lane * 512] = f2b(e0 * inv);
  o0[(i64)(lane + 64) * 512] = f2b(e1 * inv);
}

// in-place: each warp owns one row of PL; reads fully before writing
__global__ void softmax_P_bf(const unsigned short* __restrict__ PL, unsigned short* __restrict__ P) {
  i64 gw = ((i64)blockIdx.x * blockDim.x + threadIdx.x) >> 6;
  int lane = threadIdx.x & 63;
  if (gw >= 98304) return;
  const unsigned short* p = PL + gw * 128;
  float x0 = b2f(p[lane]) * TEMP_ISQ, x1 = b2f(p[lane + 64]) * TEMP_ISQ;
  float mx = fmaxf(x0, x1);
  #pragma unroll
  for (int o = 32; o; o >>= 1) mx = fmaxf(mx, __shfl_xor(mx, o));
  float e0 = expf(x0 - mx), e1 = expf(x1 - mx);
  float s = e0 + e1;
  #pragma unroll
  for (int o = 32; o; o >>= 1) s += __shfl_xor(s, o);
  float inv = 1.f / s;
  P[gw * 128 + lane] = f2b(e0 * inv);
  P[gw * 128 + lane + 64] = f2b(e1 * inv);
}

__global__ void apool_kernel(const float* __restrict__ emomean, const float* __restrict__ agg,
                             float* __restrict__ Apool) {
  int gw = (int)(((i64)blockIdx.x * blockDim.x + threadIdx.x) >> 6);
  int lane = threadIdx.x & 63;
  if (gw >= 32 * 128) return;
  int b = gw >> 7, k = gw & 127;
  const float* ag = agg + ((i64)b * 128 + k) * 1024;
  const float* em = emomean + (i64)b * 1024;
  float s = 0.f;
  #pragma unroll
  for (int j = 0; j < 16; ++j) { int e = j * 64 + lane; s += em[e] * ag[e]; }
  #pragma unroll
  for (int o = 32; o; o >>= 1) s += __shfl_down(s, o);
  if (!lane) Apool[gw] = s;
}

__global__ void route1_kernel(const float* __restrict__ Apool, const float* __restrict__ agg,
                              float* __restrict__ routePart) {
  int b = blockIdx.z, kc = blockIdx.y;
  int e = blockIdx.x * 256 + threadIdx.x;
  __shared__ float Ap[32];
  if (threadIdx.x < 32) Ap[threadIdx.x] = Apool[b * 128 + kc * 32 + threadIdx.x];
  __syncthreads();
  const float* ag = agg + ((i64)b * 128 + kc * 32) * 1024 + e;
  float s = 0.f;
  #pragma unroll
  for (int k = 0; k < 32; ++k) s += Ap[k] * ag[(i64)k * 1024];
  routePart[((i64)kc * 32 + b) * 1024 + e] = s;
}
__global__ void route2_kernel(const float* __restrict__ routePart, float* __restrict__ route) {
  int b = blockIdx.y, e = blockIdx.x * 256 + threadIdx.x;
  float s = 0.f;
  #pragma unroll
  for (int kc = 0; kc < 4; ++kc) s += routePart[((i64)kc * 32 + b) * 1024 + e];
  route[b * 1024 + e] = s;
}

__global__ void rb_kernel(const float* __restrict__ route, const float* __restrict__ eleW,
                          const float* __restrict__ eleb, float* __restrict__ rb) {
  int b = blockIdx.x, t = threadIdx.x;
  float s = 0.f;
  for (int j = t; j < 1024; j += 256) s += route[b * 1024 + j] * eleW[1024 + j];
  __shared__ float red[256];
  red[t] = s; __syncthreads();
  for (int o = 128; o > 0; o >>= 1) { if (t < o) red[t] += red[t + o]; __syncthreads(); }
  if (t == 0) rb[b] = red[0] + eleb[0];
}

__global__ void re_small(const float* __restrict__ dotE, const float* __restrict__ rb,
                         float* __restrict__ Re) {
  int i = blockIdx.x * 256 + threadIdx.x;
  Re[i] = tanhf(dotE[i] + rb[i >> 10]);
}

// ================= P consumers =================
__global__ void pmean1_kernel(const unsigned short* __restrict__ P, float* __restrict__ Ppart) {
  int bi = blockIdx.x, c = blockIdx.y, k = threadIdx.x;
  const unsigned short* p = P + ((i64)bi * 1024 + c * 128) * 128 + k;
  float s = 0.f;
  for (int l = 0; l < 128; ++l) s += b2f(p[(i64)l * 128]);
  Ppart[((i64)bi * 8 + c) * 128 + k] = s;
}
__global__ void pmean2_kernel(const float* __restrict__ Ppart, float* __restrict__ Pmean) {
  int bi = blockIdx.x, k = threadIdx.x;
  float s = 0.f;
  #pragma unroll
  for (int c = 0; c < 8; ++c) s += Ppart[((i64)bi * 8 + c) * 128 + k];
  Pmean[bi * 128 + k] = s * (1.f / 1024.f);
}

__global__ void rdiag_gate_kernel(const float* __restrict__ Pmean, const unsigned short* __restrict__ KVR,
                                  float* __restrict__ gate) {
  int b = blockIdx.x, t = threadIdx.x;  // 128 threads
  __shared__ float red[128];
  __shared__ float rd[3];
  for (int i = 0; i < 3; ++i) {
    float v = Pmean[((i64)b * 3 + i) * 128 + t] * b2f(KVR[(i64)b * 61440 + t * 480 + 476 + i]);
    red[t] = v; __syncthreads();
    for (int o = 64; o > 0; o >>= 1) { if (t < o) red[t] += red[t + o]; __syncthreads(); }
    if (t == 0) rd[i] = red[0];
    __syncthreads();
  }
  if (t == 0) {
    float m = fmaxf(rd[0], fmaxf(rd[1], rd[2]));
    float e0 = expf(rd[0] - m), e1 = expf(rd[1] - m), e2 = expf(rd[2] - m);
    float inv = 1.f / (e0 + e1 + e2);
    gate[b * 3 + 0] = e0 * inv; gate[b * 3 + 1] = e1 * inv; gate[b * 3 + 2] = e2 * inv;
  }
}

// out = b2f(emoB) * (1 + Re * sum_i gate_i * O_i)
__global__ __launch_bounds__(256)
void final_kernel(const unsigned short* __restrict__ emoB, const float* __restrict__ Re,
                  const float* __restrict__ O, const float* __restrict__ gate,
                  float* __restrict__ out) {
  i64 bl = blockIdx.x;
  int b = (int)(bl >> 10), l = (int)(bl & 1023);
  __shared__ float Gg[16];
  int t = threadIdx.x;
  if (t < 16) {
    float g0 = gate[b * 3], g1 = gate[b * 3 + 1], g2 = gate[b * 3 + 2];
    float o0 = O[((i64)(b * 3 + 0) * 1024 + l) * 28 + (t >> 2)];
    float o1 = O[((i64)(b * 3 + 1) * 1024 + l) * 28 + 4 + (t >> 1)];
    float o2 = O[((i64)(b * 3 + 2) * 1024 + l) * 28 + 12 + t];
    Gg[t] = g0 * o0 + g1 * o1 + g2 * o2;
  }
  __syncthreads();
  float re = Re[bl];
  ushort4 e4 = ((const ushort4*)(emoB + bl * 1024))[t];
  float g = 1.f + re * Gg[t >> 4];
  ((float4*)(out + bl * 1024))[t] =
      make_float4(b2f(e4.x) * g, b2f(e4.y) * g, b2f(e4.z) * g, b2f(e4.w) * g);
}

// ================= launcher =================
extern "C" void kernel_launch(void* const* d_in, const int* in_sizes, int n_in,
                              void* d_out, int out_size, void* d_ws, size_t ws_size,
                              hipStream_t stream) {
  const float* emo     = (const float*)d_in[0];
  const float* phr     = (const float*)d_in[1];
  const float* video   = (const float*)d_in[2];
  const float* w_v_W   = (const float*)d_in[3];
  const float* w_v_b   = (const float*)d_in[4];
  const float* agg_a_W = (const float*)d_in[5];
  const float* agg_a_b = (const float*)d_in[6];
  const float* agg_c_W = (const float*)d_in[7];
  const float* agg_c_b = (const float*)d_in[8];
  const float* ele_W   = (const float*)d_in[9];
  const float* ele_b   = (const float*)d_in[10];
  const float* wq_W    = (const float*)d_in[11];
  const float* wq_b    = (const float*)d_in[12];
  const float* wk_W    = (const float*)d_in[13];
  const float* wk_b    = (const float*)d_in[14];
  const float* wv_W    = (const float*)d_in[15];
  const float* wv_b    = (const float*)d_in[16];
  const float* wr_W    = (const float*)d_in[17];
  const float* wr_b    = (const float*)d_in[18];

  char* ws = (char*)d_ws;
  // ---- region map (bytes) ----
  // emoB [0,67.1M) stays LIVE until final_kernel (no overlays).
  const i64 oEmoB    = 0;            // ushort [32,1024,1024] 67,108,864
  const i64 oCombine = 67108864;     // ushort [32,512,1024] 33,554,432 (dead after G3')
  const i64 oPL      = 67108864;     //   overlay: ushort [96,1024,128]; softmax_P runs IN-PLACE -> P
  const i64 oPooled  = 100663296;    // ushort [32,256,1024] (dead after G1)
  const i64 oLogitsA = 100663296;    //   overlay: float [32,512,128] (dead after softmax_attn_a)
  const i64 oAggF    = 100663296;    //   overlay: float [32,128,1024] (dead after route1)
  const i64 oO       = 100663296;    //   overlay: float [96,1024,28] 11,010,048 (written after route1)
  const i64 oCT      = 117440512;    // ushort [32,1024,512] (dead after G4)
  const i64 oQ       = 117440512;    //   overlay: ushort [32,1024,448] 29,360,128
  const i64 oAttnAT  = 150994944;    // ushort [32,128,512] 4,194,304
  const i64 oAggB    = 155189248;    // ushort [32,128,1024] 8,388,608
  const i64 oWvT     = 163577856;    // 2,097,152
  const i64 oAaT     = 165675008;    // 262,144
  const i64 oAcT     = 165937152;    // 2,097,152
  const i64 oWqT     = 168034304;    // 1,048,576
  const i64 oKvrT    = 169082880;    // 1,048,576
  const i64 oKVR     = 170131456;    // ushort [32,128,480] 3,932,160
  const i64 oVT      = 174063616;    // ushort [32,128,128] 1,048,576
  const i64 oKvrB    = 175112192;    // 4,096
  const i64 oEmomean = 175116288;    // 131,072
  const i64 oColPart = 175247360;    // float [32,16,1024] 2,097,152
  const i64 oDotE    = 177344512;    // 131,072
  const i64 oApool   = 177475584;    // 16,384
  const i64 oRoutePt = 177491968;    // float [4,32,1024] 524,288
  const i64 oRoute   = 178016256;    // 131,072
  const i64 oRb      = 178147328;    // 256
  const i64 oRe      = 178147584;    // 131,072
  const i64 oPpart   = 178278656;    // 393,216
  const i64 oPmean   = 178671872;    // 49,152
  const i64 oGate    = 178721024;    // 512

  unsigned short* emoB    = (unsigned short*)(ws + oEmoB);
  unsigned short* combine = (unsigned short*)(ws + oCombine);
  unsigned short* PL      = (unsigned short*)(ws + oPL);
  unsigned short* P       = PL;   // in-place softmax
  unsigned short* pooled  = (unsigned short*)(ws + oPooled);
  float*          logitsA = (float*)(ws + oLogitsA);
  float*          aggF    = (float*)(ws + oAggF);
  float*          O       = (float*)(ws + oO);
  unsigned short* CT      = (unsigned short*)(ws + oCT);
  unsigned short* Q       = (unsigned short*)(ws + oQ);
  unsigned short* attnAT  = (unsigned short*)(ws + oAttnAT);
  unsigned short* aggB    = (unsigned short*)(ws + oAggB);
  unsigned short* wvT     = (unsigned short*)(ws + oWvT);
  unsigned short* aaT     = (unsigned short*)(ws + oAaT);
  unsigned short* acT     = (unsigned short*)(ws + oAcT);
  unsigned short* wqT     = (unsigned short*)(ws + oWqT);
  unsigned short* kvrT    = (unsigned short*)(ws + oKvrT);
  unsigned short* KVR     = (unsigned short*)(ws + oKVR);
  unsigned short* VT      = (unsigned short*)(ws + oVT);
  float*          kvrB    = (float*)(ws + oKvrB);
  float*          emomean = (float*)(ws + oEmomean);
  float*          colPart = (float*)(ws + oColPart);
  float*          dotE    = (float*)(ws + oDotE);
  float*          Apool   = (float*)(ws + oApool);
  float*          routePt = (float*)(ws + oRoutePt);
  float*          route   = (float*)(ws + oRoute);
  float*          rbv     = (float*)(ws + oRb);
  float*          Re      = (float*)(ws + oRe);
  float*          Ppart   = (float*)(ws + oPpart);
  float*          Pmean   = (float*)(ws + oPmean);
  float*          gate    = (float*)(ws + oGate);

  dim3 blk(256);

  // fused emo pass: colPart + dotE + emoB
  emo_pass1<<<dim3(16, 32), blk, 0, stream>>>(emo, ele_W, emoB, colPart, dotE);

  // weight prep
  transpose_w<<<dim3(32, 32), blk, 0, stream>>>(w_v_W, wvT, 1024, 1024, 1024);
  transpose_w<<<dim3(4, 32),  blk, 0, stream>>>(agg_a_W, aaT, 1024, 128, 128);
  transpose_w<<<dim3(32, 32), blk, 0, stream>>>(agg_c_W, acT, 1024, 1024, 1024);
  transpose_w<<<dim3(16, 32), blk, 0, stream>>>(wq_W, wqT, 1024, 448, 512);
  transpose_w<<<dim3(14, 32), blk, 0, stream>>>(wk_W, kvrT, 1024, 448, 448);
  transpose_w<<<dim3(1, 32),  blk, 0, stream>>>(wv_W, kvrT + (i64)448 * 1024, 1024, 28, 28);
  transpose_w<<<dim3(2, 32),  blk, 0, stream>>>(wr_W, kvrT + (i64)476 * 1024, 1024, 3, 36);
  kvr_bias_kernel<<<2, blk, 0, stream>>>(wk_b, wv_b, wr_b, kvrB);

  // feature aggregation
  pool_phr<<<8192, blk, 0, stream>>>(phr, pooled);
  vconv<<<8192, blk, 0, stream>>>(video, combine);
  gemm_mfma<1, 1, 0, 1><<<dim3(8, 2, 32), blk, 0, stream>>>(pooled, 262144, wvT, 0, w_v_b,
      (void*)combine, 524288, nullptr, 0, 1024, 1024, 1024, 1024, 1024, nullptr, 0);
  gemm_mfma<1, 0, 0, 1><<<dim3(1, 4, 32), blk, 0, stream>>>(combine, 524288, aaT, 0, agg_a_b,
      (void*)logitsA, 65536, nullptr, 0, 128, 1024, 1024, 1024, 128, nullptr, 0);
  softmax_attn_a<<<4096, blk, 0, stream>>>(logitsA, attnAT);
  gemm_mfma<2, 1, 0, 1><<<dim3(4, 8, 32), blk, 0, stream>>>(acT, 0, combine, 524288, agg_c_b,
      (void*)CT, 524288, nullptr, 0, 512, 1024, 1024, 1024, 512, nullptr, 0);
  gemm_mfma<0, 2, 0, 1><<<dim3(8, 1, 32), blk, 0, stream>>>(attnAT, 65536, CT, 524288, nullptr,
      (void*)aggF, 131072, aggB, 131072, 1024, 512, 512, 512, 1024, nullptr, 0);

  // element routing (fp32)
  colmean2<<<dim3(4, 32), blk, 0, stream>>>(colPart, emomean);
  apool_kernel<<<1024, blk, 0, stream>>>(emomean, aggF, Apool);
  route1_kernel<<<dim3(4, 4, 32), blk, 0, stream>>>(Apool, aggF, routePt);
  route2_kernel<<<dim3(4, 32), blk, 0, stream>>>(routePt, route);
  rb_kernel<<<32, blk, 0, stream>>>(route, ele_W, ele_b, rbv);
  re_small<<<128, blk, 0, stream>>>(dotE, rbv, Re);

  // KVR = agg @ [wk|wv|wr] + bias
  gemm_mfma<1, 1, 0, 1><<<dim3(4, 1, 32), blk, 0, stream>>>(aggB, 131072, kvrT, 0, kvrB,
      (void*)KVR, 61440, nullptr, 0, 480, 1024, 1024, 1024, 480, nullptr, 0);
  vt_fill<<<dim3(64, 32), blk, 0, stream>>>(KVR, VT);
  // G6: Q = Re * (emoB @ wq) + b
  gemm_mfma<1, 1, 1, 1><<<dim3(4, 8, 32), blk, 0, stream>>>(emoB, 1048576, wqT, 0, wq_b,
      (void*)Q, 458752, nullptr, 0, 448, 1024, 1024, 1024, 448, Re, 1024);

  // G8: PL[i] = Q_blk @ K_blk^T (bf16 logits)
  const int doffs[3] = {0, 256, 384};
  const int kds[3]   = {256, 128, 64};
  for (int i = 0; i < 3; ++i) {
    gemm_mfma<0, 1, 0, 1><<<dim3(1, 8, 32), blk, 0, stream>>>(Q + doffs[i], 458752,
        KVR + doffs[i], 61440, nullptr,
        (void*)(PL + (i64)i * 131072), 393216, nullptr, 0, 128, kds[i], 448, 480, 128, nullptr, 0);
  }
  softmax_P_bf<<<24576, blk, 0, stream>>>(PL, P);
  pmean1_kernel<<<dim3(96, 8), 128, 0, stream>>>(P, Ppart);
  pmean2_kernel<<<96, 128, 0, stream>>>(Ppart, Pmean);
  // OV: O = tanh((P @ VT^T)/3)
  gemm_mfma<0, 3, 0, 3><<<dim3(1, 8, 96), blk, 0, stream>>>(P, 131072, VT, 16384, nullptr,
      (void*)O, 28672, nullptr, 0, 28, 128, 128, 128, 28, nullptr, 0);
  rdiag_gate_kernel<<<32, 128, 0, stream>>>(Pmean, KVR, gate);
  final_kernel<<<32768, blk, 0, stream>>>(emoB, Re, O, gate, (float*)d_out);
}

// Round 5
// 453.046 us; speedup vs baseline: 5.1808x; 1.0431x over previous
//
#include <hip/hip_runtime.h>
#include <math.h>

typedef long long i64;
typedef __attribute__((ext_vector_type(8))) short bf16x8;
typedef __attribute__((ext_vector_type(4))) float f32x4;

#define TEMP_ISQ 0.047245559f   // 1/sqrt(448)

__device__ __forceinline__ unsigned short f2b(float x) {
  union { float f; unsigned u; } a; a.f = x;
  return (unsigned short)((a.u + 0x7fffu + ((a.u >> 16) & 1u)) >> 16);
}
__device__ __forceinline__ float b2f(unsigned short b) {
  union { float f; unsigned u; } a; a.u = ((unsigned)b) << 16; return a.f;
}

// ================= NT bf16 MFMA GEMM =================
// out[M,N] = A[M,K] @ BT[N,K]^T (+bias). 128x128 tile, BK=64, 4 waves.
// T1 chunked XCD swizzle on flattened block id (requires nwg % 8 == 0).
// BIAS: 0 none, 1 col bias[col], 2 row bias[row]
// OUTM: 0 fp32, 1 bf16, 2 both (fp32 Ob + bf16 O2b), 3 fp32 tanh(acc/3)
// RS:   1 -> v *= tanhf(rowScale[z*sRS + row] + rsAdd[z])
// BZDIV: B batch index = z / BZDIV
// XMODE: 1 -> G8 mode: z' -> (b=z'/3, i=z'%3); A/B offset doffs[i], Kd from table
template<int BIAS, int OUTM, int RS, int BZDIV, int XMODE = 0>
__global__ __launch_bounds__(256)
void gemm_mfma(const unsigned short* __restrict__ Ab, i64 sA,
               const unsigned short* __restrict__ Bb, i64 sB,
               const float* __restrict__ bias,
               void* __restrict__ Ob, i64 sO,
               unsigned short* __restrict__ O2b, i64 sO2,
               int Nn, int Kd, int ldA, int ldB, int ldO,
               const float* __restrict__ rowScale, i64 sRS,
               const float* __restrict__ rsAdd)
{
  __shared__ unsigned short As[8192];   // 128 x 64 bf16 (16KB)
  __shared__ unsigned short Bs[8192];
  const int tid = threadIdx.x;
  const int w = tid >> 6, lane = tid & 63;

  // T1 chunked XCD swizzle
  const int gx = gridDim.x, gy = gridDim.y;
  int nwg = gx * gy * gridDim.z;
  int bid = blockIdx.x + gx * (blockIdx.y + gy * blockIdx.z);
  int L = bid;
  if ((nwg & 7) == 0) L = (bid & 7) * (nwg >> 3) + (bid >> 3);
  const int bx = L % gx;
  int rem = L / gx;
  const int by = rem % gy;
  const int z  = rem / gy;

  const int m0 = by * 128, n0 = bx * 128;
  const unsigned short* A;
  const unsigned short* B;
  int KdL = Kd;
  if (XMODE == 1) {
    int bb = z / 3, ii = z - bb * 3;
    const int dof_[3] = {0, 256, 384};
    const int kdt_[3] = {256, 128, 64};
    A = Ab + dof_[ii] + (i64)bb * sA;
    B = Bb + dof_[ii] + (i64)bb * sB;
    KdL = kdt_[ii];
  } else {
    A = Ab + (i64)z * sA;
    B = Bb + (i64)(BZDIV == 1 ? z : z / BZDIV) * sB;
  }
  const int wr = w >> 1, wc = w & 1;
  const int rS = tid >> 3, sS = tid & 7;       // stage: row, slot
  const int cL = lane & 15, sl = lane >> 4;

  f32x4 acc[4][4];
  #pragma unroll
  for (int i = 0; i < 4; ++i)
    #pragma unroll
    for (int j = 0; j < 4; ++j) acc[i][j] = (f32x4){0.f, 0.f, 0.f, 0.f};

  for (int k0 = 0; k0 < KdL; k0 += 64) {
    // stage 128x64 tiles; LDS linear dest, source slot pre-XOR'd (rule #21)
    #pragma unroll
    for (int q = 0; q < 4; ++q) {
      int r = rS + q * 32;
      int sg = sS ^ (r & 7);
      const unsigned short* sa = A + (i64)(m0 + r) * ldA + k0 + sg * 8;
      const unsigned short* sb = B + (i64)(n0 + r) * ldB + k0 + sg * 8;
      __builtin_amdgcn_global_load_lds(
          (__attribute__((address_space(1))) void*)sa,
          (__attribute__((address_space(3))) void*)&As[r * 64 + sS * 8], 16, 0, 0);
      __builtin_amdgcn_global_load_lds(
          (__attribute__((address_space(1))) void*)sb,
          (__attribute__((address_space(3))) void*)&Bs[r * 64 + sS * 8], 16, 0, 0);
    }
    __syncthreads();
    bf16x8 af[2][4], bfv[2][4];
    #pragma unroll
    for (int kk = 0; kk < 2; ++kk) {
      #pragma unroll
      for (int mi = 0; mi < 4; ++mi) {
        int rr = wr * 64 + mi * 16 + cL;
        int ph = (kk * 4 + sl) ^ (rr & 7);
        af[kk][mi] = *(const bf16x8*)&As[rr * 64 + ph * 8];
      }
      #pragma unroll
      for (int ni = 0; ni < 4; ++ni) {
        int rr = wc * 64 + ni * 16 + cL;
        int ph = (kk * 4 + sl) ^ (rr & 7);
        bfv[kk][ni] = *(const bf16x8*)&Bs[rr * 64 + ph * 8];
      }
    }
    #pragma unroll
    for (int kk = 0; kk < 2; ++kk)
      #pragma unroll
      for (int mi = 0; mi < 4; ++mi)
        #pragma unroll
        for (int ni = 0; ni < 4; ++ni)
          acc[mi][ni] = __builtin_amdgcn_mfma_f32_16x16x32_bf16(af[kk][mi], bfv[kk][ni], acc[mi][ni], 0, 0, 0);
    __syncthreads();
  }

  // D layout: col=lane&15, row=(lane>>4)*4+reg
  #pragma unroll
  for (int mi = 0; mi < 4; ++mi) {
    const int rowb = m0 + wr * 64 + mi * 16 + sl * 4;
    #pragma unroll
    for (int ni = 0; ni < 4; ++ni) {
      const int col = n0 + wc * 64 + ni * 16 + cL;
      if (col < Nn) {
        float bc = (BIAS == 1) ? bias[col] : 0.f;
        #pragma unroll
        for (int rg = 0; rg < 4; ++rg) {
          float v = acc[mi][ni][rg];
          if (RS) v *= tanhf(rowScale[(i64)z * sRS + rowb + rg] + rsAdd[z]);
          v += bc;
          if (BIAS == 2) v += bias[rowb + rg];
          i64 oidx = (i64)(rowb + rg) * ldO + col;
          if (OUTM == 0)      ((float*)Ob)[(i64)z * sO + oidx] = v;
          else if (OUTM == 1) ((unsigned short*)Ob)[(i64)z * sO + oidx] = f2b(v);
          else if (OUTM == 3) ((float*)Ob)[(i64)z * sO + oidx] = tanhf(v * (1.f / 3.f));
          else {
            ((float*)Ob)[(i64)z * sO + oidx] = v;
            O2b[(i64)z * sO2 + oidx] = f2b(v);
          }
        }
      }
    }
  }
}

// ================= fused emo pass =================
// 2048 blocks (16 rows each): colPart [32][64][1024], dotE, emoB
__global__ __launch_bounds__(256)
void emo_pass1(const float* __restrict__ emo, const float* __restrict__ eleW,
               unsigned short* __restrict__ emoB, float* __restrict__ colPart,
               float* __restrict__ dotE) {
  int b = blockIdx.y, lc = blockIdx.x;   // 64 chunks x 16 rows
  int t = threadIdx.x, lane = t & 63, w = t >> 6;
  float4 w4 = ((const float4*)eleW)[t];
  float4 acc = make_float4(0.f, 0.f, 0.f, 0.f);
  __shared__ float dw[16][4];
  const float4* src = (const float4*)emo + ((i64)b * 1024 + lc * 16) * 256;
  ushort4* dst = (ushort4*)emoB + ((i64)b * 1024 + lc * 16) * 256;
  #pragma unroll 4
  for (int lr = 0; lr < 16; ++lr) {
    float4 v = src[lr * 256 + t];
    acc.x += v.x; acc.y += v.y; acc.z += v.z; acc.w += v.w;
    float d = v.x * w4.x + v.y * w4.y + v.z * w4.z + v.w * w4.w;
    #pragma unroll
    for (int o = 32; o; o >>= 1) d += __shfl_xor(d, o);
    if (!lane) dw[lr][w] = d;
    ushort4 o4; o4.x = f2b(v.x); o4.y = f2b(v.y); o4.z = f2b(v.z); o4.w = f2b(v.w);
    dst[lr * 256 + t] = o4;
  }
  __syncthreads();
  if (t < 16) dotE[(i64)b * 1024 + lc * 16 + t] = dw[t][0] + dw[t][1] + dw[t][2] + dw[t][3];
  ((float4*)colPart)[((i64)b * 64 + lc) * 256 + t] = acc;
}

__global__ void colmean2(const float* __restrict__ colPart, float* __restrict__ emomean) {
  int b = blockIdx.y, e = blockIdx.x * 256 + threadIdx.x;
  float s = 0.f;
  #pragma unroll 8
  for (int lc = 0; lc < 64; ++lc) s += colPart[((i64)b * 64 + lc) * 1024 + e];
  emomean[b * 1024 + e] = s * (1.f / 1024.f);
}

// ================= prep kernels =================
// all 7 weight transposes in one launch. grid (101, 32).
__global__ __launch_bounds__(256)
void transpose_all(const float* __restrict__ w_v_W, const float* __restrict__ agg_a_W,
                   const float* __restrict__ agg_c_W, const float* __restrict__ wq_W,
                   const float* __restrict__ wk_W, const float* __restrict__ wv_W,
                   const float* __restrict__ wr_W,
                   unsigned short* __restrict__ wvT, unsigned short* __restrict__ aaT,
                   unsigned short* __restrict__ acT, unsigned short* __restrict__ wqT,
                   unsigned short* __restrict__ kvrT) {
  __shared__ float T[32][33];
  int bx = blockIdx.x;
  const float* in; unsigned short* out; int N, Npad, s0;
  if (bx < 32)      { in = w_v_W;   out = wvT;                     N = 1024; Npad = 1024; s0 = 0; }
  else if (bx < 36) { in = agg_a_W; out = aaT;                     N = 128;  Npad = 128;  s0 = 32; }
  else if (bx < 68) { in = agg_c_W; out = acT;                     N = 1024; Npad = 1024; s0 = 36; }
  else if (bx < 84) { in = wq_W;    out = wqT;                     N = 448;  Npad = 512;  s0 = 68; }
  else if (bx < 98) { in = wk_W;    out = kvrT;                    N = 448;  Npad = 448;  s0 = 84; }
  else if (bx < 99) { in = wv_W;    out = kvrT + (i64)448 * 1024;  N = 28;   Npad = 28;   s0 = 98; }
  else              { in = wr_W;    out = kvrT + (i64)476 * 1024;  N = 3;    Npad = 36;   s0 = 99; }
  int n0 = (bx - s0) * 32, k0 = blockIdx.y * 32;
  int t = threadIdx.x;
  #pragma unroll
  for (int p = 0; p < 4; ++p) {
    int idx = t + 256 * p; int kk = idx >> 5, nn = idx & 31;
    float v = 0.f;
    if (n0 + nn < N) v = in[(i64)(k0 + kk) * N + (n0 + nn)];
    T[nn][kk] = v;
  }
  __syncthreads();
  #pragma unroll
  for (int p = 0; p < 4; ++p) {
    int idx = t + 256 * p; int nn = idx >> 5, kk = idx & 31;
    if (n0 + nn < Npad) out[(i64)(n0 + nn) * 1024 + (k0 + kk)] = f2b(T[nn][kk]);
  }
}

__global__ void kvr_bias_kernel(const float* wkb, const float* wvb, const float* wrb, float* out) {
  int t = blockIdx.x * 256 + threadIdx.x;
  if (t >= 480) return;
  out[t] = (t < 448) ? wkb[t] : (t < 476) ? wvb[t - 448] : (t < 479) ? wrb[t - 476] : 0.f;
}

__global__ void pool_phr(const float* __restrict__ phr, unsigned short* __restrict__ out) {
  i64 idx = (i64)blockIdx.x * 256 + threadIdx.x;
  if (idx >= 2097152) return;
  i64 bm = idx >> 8; int c = (int)(idx & 255);
  i64 b = bm >> 8, m = bm & 255;
  const float4* r0 = (const float4*)(phr + (b * 512 + 2 * m) * 1024) + c;
  const float4* r1 = (const float4*)(phr + (b * 512 + 2 * m + 1) * 1024) + c;
  float4 a = *r0, d = *r1;
  ushort4 o;
  o.x = f2b(0.5f * (a.x + d.x)); o.y = f2b(0.5f * (a.y + d.y));
  o.z = f2b(0.5f * (a.z + d.z)); o.w = f2b(0.5f * (a.w + d.w));
  ((ushort4*)out)[idx] = o;
}

__global__ void vconv(const float* __restrict__ video, unsigned short* __restrict__ combine) {
  i64 idx = (i64)blockIdx.x * 256 + threadIdx.x;
  if (idx >= 2097152) return;
  i64 b = idx >> 16, r = idx & 65535;
  float4 v = ((const float4*)video)[idx];
  ushort4 o;
  o.x = f2b(v.x); o.y = f2b(v.y); o.z = f2b(v.z); o.w = f2b(v.w);
  ((ushort4*)combine)[b * 131072 + 65536 + r] = o;
}

// VT[b][n][k] = KVR[b][k][448+n] (n<28), 0 pad to 128 rows
__global__ void vt_fill(const unsigned short* __restrict__ KVR, unsigned short* __restrict__ VT) {
  int b = blockIdx.y;
  int idx = blockIdx.x * 256 + threadIdx.x;
  int n = idx >> 7, k = idx & 127;
  unsigned short v = 0;
  if (n < 28) v = KVR[(i64)b * 61440 + k * 480 + 448 + n];
  VT[((i64)b * 128 + n) * 128 + k] = v;
}

// ================= softmax / routing =================
__global__ void softmax_attn_a(const float* __restrict__ logits, unsigned short* __restrict__ outT) {
  int gw = (int)(((i64)blockIdx.x * blockDim.x + threadIdx.x) >> 6);
  int lane = threadIdx.x & 63;
  if (gw >= 32 * 512) return;
  int b = gw >> 9, m = gw & 511;
  const float* p = logits + (i64)gw * 128;
  float x0 = p[lane], x1 = p[lane + 64];
  float mx = fmaxf(x0, x1);
  #pragma unroll
  for (int o = 32; o; o >>= 1) mx = fmaxf(mx, __shfl_xor(mx, o));
  float e0 = expf(x0 - mx), e1 = expf(x1 - mx);
  float s = e0 + e1;
  #pragma unroll
  for (int o = 32; o; o >>= 1) s += __shfl_xor(s, o);
  float inv = 1.f / s;
  unsigned short* o0 = outT + (i64)b * 128 * 512 + m;
  o0[(i64)lane * 512] = f2b(e0 * inv);
  o0[(i64)(lane + 64) * 512] = f2b(e1 * inv);
}

// in-place: each warp owns one row of PL; reads fully before writing
__global__ void softmax_P_bf(const unsigned short* __restrict__ PL, unsigned short* __restrict__ P) {
  i64 gw = ((i64)blockIdx.x * blockDim.x + threadIdx.x) >> 6;
  int lane = threadIdx.x & 63;
  if (gw >= 98304) return;
  const unsigned short* p = PL + gw * 128;
  float x0 = b2f(p[lane]) * TEMP_ISQ, x1 = b2f(p[lane + 64]) * TEMP_ISQ;
  float mx = fmaxf(x0, x1);
  #pragma unroll
  for (int o = 32; o; o >>= 1) mx = fmaxf(mx, __shfl_xor(mx, o));
  float e0 = expf(x0 - mx), e1 = expf(x1 - mx);
  float s = e0 + e1;
  #pragma unroll
  for (int o = 32; o; o >>= 1) s += __shfl_xor(s, o);
  float inv = 1.f / s;
  P[gw * 128 + lane] = f2b(e0 * inv);
  P[gw * 128 + lane + 64] = f2b(e1 * inv);
}

__global__ void apool_kernel(const float* __restrict__ emomean, const float* __restrict__ agg,
                             float* __restrict__ Apool) {
  int gw = (int)(((i64)blockIdx.x * blockDim.x + threadIdx.x) >> 6);
  int lane = threadIdx.x & 63;
  if (gw >= 32 * 128) return;
  int b = gw >> 7, k = gw & 127;
  const float* ag = agg + ((i64)b * 128 + k) * 1024;
  const float* em = emomean + (i64)b * 1024;
  float s = 0.f;
  #pragma unroll
  for (int j = 0; j < 16; ++j) { int e = j * 64 + lane; s += em[e] * ag[e]; }
  #pragma unroll
  for (int o = 32; o; o >>= 1) s += __shfl_down(s, o);
  if (!lane) Apool[gw] = s;
}

// route[b,e] = sum_k Apool[b,k]*agg[b,k,e]  (grid (4,32))
__global__ void route_kernel(const float* __restrict__ Apool, const float* __restrict__ agg,
                             float* __restrict__ route) {
  int b = blockIdx.y;
  int e = blockIdx.x * 256 + threadIdx.x;
  __shared__ float Ap[128];
  if (threadIdx.x < 128) Ap[threadIdx.x] = Apool[b * 128 + threadIdx.x];
  __syncthreads();
  const float* ag = agg + (i64)b * 128 * 1024 + e;
  float s = 0.f;
  #pragma unroll 8
  for (int k = 0; k < 128; ++k) s += Ap[k] * ag[(i64)k * 1024];
  route[b * 1024 + e] = s;
}

__global__ void rb_kernel(const float* __restrict__ route, const float* __restrict__ eleW,
                          const float* __restrict__ eleb, float* __restrict__ rb) {
  int b = blockIdx.x, t = threadIdx.x;
  float s = 0.f;
  for (int j = t; j < 1024; j += 256) s += route[b * 1024 + j] * eleW[1024 + j];
  __shared__ float red[256];
  red[t] = s; __syncthreads();
  for (int o = 128; o > 0; o >>= 1) { if (t < o) red[t] += red[t + o]; __syncthreads(); }
  if (t == 0) rb[b] = red[0] + eleb[0];
}

// ================= P consumers =================
__global__ void pmean1_kernel(const unsigned short* __restrict__ P, float* __restrict__ Ppart) {
  int bi = blockIdx.x, c = blockIdx.y, k = threadIdx.x;
  const unsigned short* p = P + ((i64)bi * 1024 + c * 128) * 128 + k;
  float s = 0.f;
  for (int l = 0; l < 128; ++l) s += b2f(p[(i64)l * 128]);
  Ppart[((i64)bi * 8 + c) * 128 + k] = s;
}

// fused pmean2 + rdiag + gate (32 blocks x 128 threads)
__global__ void pmean2_rdiag(const float* __restrict__ Ppart, const unsigned short* __restrict__ KVR,
                             float* __restrict__ gate) {
  int b = blockIdx.x, t = threadIdx.x;
  __shared__ float red[128];
  __shared__ float rd[3];
  for (int i = 0; i < 3; ++i) {
    float s = 0.f;
    #pragma unroll
    for (int c = 0; c < 8; ++c) s += Ppart[((i64)(b * 3 + i) * 8 + c) * 128 + t];
    float v = s * (1.f / 1024.f) * b2f(KVR[(i64)b * 61440 + t * 480 + 476 + i]);
    red[t] = v; __syncthreads();
    for (int o = 64; o > 0; o >>= 1) { if (t < o) red[t] += red[t + o]; __syncthreads(); }
    if (t == 0) rd[i] = red[0];
    __syncthreads();
  }
  if (t == 0) {
    float m = fmaxf(rd[0], fmaxf(rd[1], rd[2]));
    float e0 = expf(rd[0] - m), e1 = expf(rd[1] - m), e2 = expf(rd[2] - m);
    float inv = 1.f / (e0 + e1 + e2);
    gate[b * 3 + 0] = e0 * inv; gate[b * 3 + 1] = e1 * inv; gate[b * 3 + 2] = e2 * inv;
  }
}

// out = b2f(emoB) * (1 + tanh(dotE+rb) * sum_i gate_i * O_i)
__global__ __launch_bounds__(256)
void final_kernel(const unsigned short* __restrict__ emoB, const float* __restrict__ dotE,
                  const float* __restrict__ rbv, const float* __restrict__ O,
                  const float* __restrict__ gate, float* __restrict__ out) {
  i64 bl = blockIdx.x;
  int b = (int)(bl >> 10), l = (int)(bl & 1023);
  __shared__ float Gg[16];
  int t = threadIdx.x;
  if (t < 16) {
    float g0 = gate[b * 3], g1 = gate[b * 3 + 1], g2 = gate[b * 3 + 2];
    float o0 = O[((i64)(b * 3 + 0) * 1024 + l) * 28 + (t >> 2)];
    float o1 = O[((i64)(b * 3 + 1) * 1024 + l) * 28 + 4 + (t >> 1)];
    float o2 = O[((i64)(b * 3 + 2) * 1024 + l) * 28 + 12 + t];
    Gg[t] = g0 * o0 + g1 * o1 + g2 * o2;
  }
  __syncthreads();
  float re = tanhf(dotE[bl] + rbv[b]);
  ushort4 e4 = ((const ushort4*)(emoB + bl * 1024))[t];
  float g = 1.f + re * Gg[t >> 4];
  ((float4*)(out + bl * 1024))[t] =
      make_float4(b2f(e4.x) * g, b2f(e4.y) * g, b2f(e4.z) * g, b2f(e4.w) * g);
}

// ================= launcher =================
extern "C" void kernel_launch(void* const* d_in, const int* in_sizes, int n_in,
                              void* d_out, int out_size, void* d_ws, size_t ws_size,
                              hipStream_t stream) {
  const float* emo     = (const float*)d_in[0];
  const float* phr     = (const float*)d_in[1];
  const float* video   = (const float*)d_in[2];
  const float* w_v_W   = (const float*)d_in[3];
  const float* w_v_b   = (const float*)d_in[4];
  const float* agg_a_W = (const float*)d_in[5];
  const float* agg_a_b = (const float*)d_in[6];
  const float* agg_c_W = (const float*)d_in[7];
  const float* agg_c_b = (const float*)d_in[8];
  const float* ele_W   = (const float*)d_in[9];
  const float* ele_b   = (const float*)d_in[10];
  const float* wq_W    = (const float*)d_in[11];
  const float* wq_b    = (const float*)d_in[12];
  const float* wk_W    = (const float*)d_in[13];
  const float* wk_b    = (const float*)d_in[14];
  const float* wv_W    = (const float*)d_in[15];
  const float* wv_b    = (const float*)d_in[16];
  const float* wr_W    = (const float*)d_in[17];
  const float* wr_b    = (const float*)d_in[18];

  char* ws = (char*)d_ws;
  // ---- region map (bytes) ----
  const i64 oEmoB    = 0;            // ushort [32,1024,1024] 67,108,864 (live to the end)
  const i64 oCombine = 67108864;     // ushort [32,512,1024] (dead after G3')
  const i64 oPL      = 67108864;     //   overlay: ushort [96,1024,128]; softmax IN-PLACE -> P
  const i64 oPooled  = 100663296;    // ushort [32,256,1024] (dead after G1)
  const i64 oLogitsA = 100663296;    //   overlay: float [32,512,128] (dead after softmax_attn_a)
  const i64 oAggF    = 100663296;    //   overlay: float [32,128,1024] (dead after route)
  const i64 oO       = 100663296;    //   overlay: float [96,1024,28] (written after route)
  const i64 oCT      = 117440512;    // ushort [32,1024,512] (dead after G4)
  const i64 oQ       = 117440512;    //   overlay: ushort [32,1024,448]
  const i64 oAttnAT  = 150994944;    // ushort [32,128,512] 4,194,304
  const i64 oAggB    = 155189248;    // ushort [32,128,1024] 8,388,608
  const i64 oWvT     = 163577856;    // 2,097,152
  const i64 oAaT     = 165675008;    // 262,144
  const i64 oAcT     = 165937152;    // 2,097,152
  const i64 oWqT     = 168034304;    // 1,048,576
  const i64 oKvrT    = 169082880;    // 1,048,576
  const i64 oKVR     = 170131456;    // ushort [32,128,480] 3,932,160
  const i64 oVT      = 174063616;    // ushort [32,128,128] 1,048,576
  const i64 oKvrB    = 175112192;    // 4,096
  const i64 oEmomean = 175116288;    // 131,072
  const i64 oColPart = 175247360;    // float [32,64,1024] 8,388,608
  const i64 oDotE    = 183635968;    // 131,072
  const i64 oApool   = 183767040;    // 16,384
  const i64 oRoute   = 183783424;    // 131,072
  const i64 oRb      = 183914496;    // 256
  const i64 oPpart   = 183914752;    // 393,216
  const i64 oGate    = 184307968;    // 512

  unsigned short* emoB    = (unsigned short*)(ws + oEmoB);
  unsigned short* combine = (unsigned short*)(ws + oCombine);
  unsigned short* PL      = (unsigned short*)(ws + oPL);
  unsigned short* P       = PL;   // in-place softmax
  unsigned short* pooled  = (unsigned short*)(ws + oPooled);
  float*          logitsA = (float*)(ws + oLogitsA);
  float*          aggF    = (float*)(ws + oAggF);
  float*          O       = (float*)(ws + oO);
  unsigned short* CT      = (unsigned short*)(ws + oCT);
  unsigned short* Q       = (unsigned short*)(ws + oQ);
  unsigned short* attnAT  = (unsigned short*)(ws + oAttnAT);
  unsigned short* aggB    = (unsigned short*)(ws + oAggB);
  unsigned short* wvT     = (unsigned short*)(ws + oWvT);
  unsigned short* aaT     = (unsigned short*)(ws + oAaT);
  unsigned short* acT     = (unsigned short*)(ws + oAcT);
  unsigned short* wqT     = (unsigned short*)(ws + oWqT);
  unsigned short* kvrT    = (unsigned short*)(ws + oKvrT);
  unsigned short* KVR     = (unsigned short*)(ws + oKVR);
  unsigned short* VT      = (unsigned short*)(ws + oVT);
  float*          kvrB    = (float*)(ws + oKvrB);
  float*          emomean = (float*)(ws + oEmomean);
  float*          colPart = (float*)(ws + oColPart);
  float*          dotE    = (float*)(ws + oDotE);
  float*          Apool   = (float*)(ws + oApool);
  float*          route   = (float*)(ws + oRoute);
  float*          rbv     = (float*)(ws + oRb);
  float*          Ppart   = (float*)(ws + oPpart);
  float*          gate    = (float*)(ws + oGate);

  dim3 blk(256);

  // fused emo pass: colPart + dotE + emoB (2048 blocks)
  emo_pass1<<<dim3(64, 32), blk, 0, stream>>>(emo, ele_W, emoB, colPart, dotE);

  // weight prep (single launch) + bias pack
  transpose_all<<<dim3(101, 32), blk, 0, stream>>>(w_v_W, agg_a_W, agg_c_W, wq_W, wk_W, wv_W, wr_W,
                                                   wvT, aaT, acT, wqT, kvrT);
  kvr_bias_kernel<<<2, blk, 0, stream>>>(wk_b, wv_b, wr_b, kvrB);

  // feature aggregation
  pool_phr<<<8192, blk, 0, stream>>>(phr, pooled);
  vconv<<<8192, blk, 0, stream>>>(video, combine);
  gemm_mfma<1, 1, 0, 1><<<dim3(8, 2, 32), blk, 0, stream>>>(pooled, 262144, wvT, 0, w_v_b,
      (void*)combine, 524288, nullptr, 0, 1024, 1024, 1024, 1024, 1024, nullptr, 0, nullptr);
  gemm_mfma<1, 0, 0, 1><<<dim3(1, 4, 32), blk, 0, stream>>>(combine, 524288, aaT, 0, agg_a_b,
      (void*)logitsA, 65536, nullptr, 0, 128, 1024, 1024, 1024, 128, nullptr, 0, nullptr);
  softmax_attn_a<<<4096, blk, 0, stream>>>(logitsA, attnAT);
  gemm_mfma<2, 1, 0, 1><<<dim3(4, 8, 32), blk, 0, stream>>>(acT, 0, combine, 524288, agg_c_b,
      (void*)CT, 524288, nullptr, 0, 512, 1024, 1024, 1024, 512, nullptr, 0, nullptr);
  gemm_mfma<0, 2, 0, 1><<<dim3(8, 1, 32), blk, 0, stream>>>(attnAT, 65536, CT, 524288, nullptr,
      (void*)aggF, 131072, aggB, 131072, 1024, 512, 512, 512, 1024, nullptr, 0, nullptr);

  // element routing (fp32)
  colmean2<<<dim3(4, 32), blk, 0, stream>>>(colPart, emomean);
  apool_kernel<<<1024, blk, 0, stream>>>(emomean, aggF, Apool);
  route_kernel<<<dim3(4, 32), blk, 0, stream>>>(Apool, aggF, route);
  rb_kernel<<<32, blk, 0, stream>>>(route, ele_W, ele_b, rbv);

  // KVR = agg @ [wk|wv|wr] + bias
  gemm_mfma<1, 1, 0, 1><<<dim3(4, 1, 32), blk, 0, stream>>>(aggB, 131072, kvrT, 0, kvrB,
      (void*)KVR, 61440, nullptr, 0, 480, 1024, 1024, 1024, 480, nullptr, 0, nullptr);
  vt_fill<<<dim3(64, 32), blk, 0, stream>>>(KVR, VT);
  // G6: Q = tanh(dotE+rb) * (emoB @ wq) + b  (row-scale epilogue)
  gemm_mfma<1, 1, 1, 1><<<dim3(4, 8, 32), blk, 0, stream>>>(emoB, 1048576, wqT, 0, wq_b,
      (void*)Q, 458752, nullptr, 0, 448, 1024, 1024, 1024, 448, dotE, 1024, rbv);

  // G8 (fused, z=96): PL[b,i] = Q_blk @ K_blk^T (bf16 logits)
  gemm_mfma<0, 1, 0, 1, 1><<<dim3(1, 8, 96), blk, 0, stream>>>(Q, 458752, KVR, 61440, nullptr,
      (void*)PL, 131072, nullptr, 0, 128, 0, 448, 480, 128, nullptr, 0, nullptr);

  softmax_P_bf<<<24576, blk, 0, stream>>>(PL, P);
  pmean1_kernel<<<dim3(96, 8), 128, 0, stream>>>(P, Ppart);
  // OV: O = tanh((P @ VT^T)/3)
  gemm_mfma<0, 3, 0, 3><<<dim3(1, 8, 96), blk, 0, stream>>>(P, 131072, VT, 16384, nullptr,
      (void*)O, 28672, nullptr, 0, 28, 128, 128, 128, 28, nullptr, 0, nullptr);
  pmean2_rdiag<<<32, 128, 0, stream>>>(Ppart, KVR, gate);
  final_kernel<<<32768, blk, 0, stream>>>(emoB, dotE, rbv, O, gate, (float*)d_out);
}